// Round 7
// baseline (228.150 us; speedup 1.0000x reference)
//
#include <hip/hip_runtime.h>

#define NN 50000
#define NE 800000
#define FD 128
#define NG 512
#define NC 10

// bucketed CSR build
#define NBUCK 98            // ceil(50000/512)
#define BSHIFT 9            // 512 nodes per bucket
#define BSTRIDE 10240       // slots per bucket region (mean 8192, sd ~90)
#define P1_EPB 4096         // edges per pass1 block
#define P1_BLOCKS ((NE + P1_EPB - 1) / P1_EPB)  // 196

typedef __attribute__((ext_vector_type(8))) short bf16x8;
typedef __attribute__((ext_vector_type(4))) float f32x4;

// ---------------- bf16 helpers ----------------

__device__ __forceinline__ float bf2f(unsigned short u) {
  return __uint_as_float(((unsigned int)u) << 16);
}
__device__ __forceinline__ unsigned short f2bf(float f) {
  unsigned int b = __float_as_uint(f);
  b += 0x7FFF + ((b >> 16) & 1);   // round-to-nearest-even
  return (unsigned short)(b >> 16);
}

// ---------------- setup ----------------

__global__ __launch_bounds__(128) void init_kernel(int* __restrict__ gcursor) {
  int i = threadIdx.x;
  if (i < NBUCK) gcursor[i] = i * BSTRIDE;
}

// pass1: bucket-scatter packed (src16|dst16) records with per-block LDS grouping.
__global__ __launch_bounds__(1024) void pass1_kernel(const int* __restrict__ ei,
                                                     int* __restrict__ gcursor,
                                                     unsigned int* __restrict__ bucketBuf) {
  __shared__ unsigned int recs[P1_EPB];
  __shared__ unsigned int grp[P1_EPB];
  __shared__ int bh[NBUCK];
  __shared__ int boff[NBUCK];
  __shared__ int bcur[NBUCK];
  __shared__ int gbase[NBUCK];
  __shared__ int bscan[128];

  int tid = threadIdx.x;
  int e0 = blockIdx.x * P1_EPB;
  int ne = NE - e0; if (ne > P1_EPB) ne = P1_EPB;

  if (tid < NBUCK) bh[tid] = 0;
  __syncthreads();

  for (int i = tid; i < ne; i += 1024) {
    int s = ei[e0 + i];
    int d = ei[NE + e0 + i];
    atomicAdd(&bh[d >> BSHIFT], 1);
    recs[i] = (unsigned int)s | ((unsigned int)d << 16);
  }
  __syncthreads();

  if (tid < 128) bscan[tid] = (tid < NBUCK) ? bh[tid] : 0;
  __syncthreads();
  for (int off = 1; off < 128; off <<= 1) {
    int v = 0;
    if (tid < 128 && tid >= off) v = bscan[tid - off];
    __syncthreads();
    if (tid < 128) bscan[tid] += v;
    __syncthreads();
  }
  if (tid < NBUCK) {
    boff[tid] = bscan[tid] - bh[tid];
    bcur[tid] = bscan[tid] - bh[tid];
    gbase[tid] = (bh[tid] > 0) ? atomicAdd(&gcursor[tid], bh[tid]) : 0;
  }
  __syncthreads();

  for (int i = tid; i < ne; i += 1024) {
    unsigned int r = recs[i];
    int b = (int)(r >> (16 + BSHIFT));
    int p = atomicAdd(&bcur[b], 1);
    grp[p] = r;
  }
  __syncthreads();

  for (int s = tid; s < ne; s += 1024) {
    int lo = 0, hi = NBUCK - 1;
    while (lo < hi) { int m = (lo + hi + 1) >> 1; if (boff[m] <= s) lo = m; else hi = m - 1; }
    bucketBuf[gbase[lo] + (s - boff[lo])] = grp[s];
  }
}

// exclusive scan of 98 bucket totals -> bbase
__global__ __launch_bounds__(128) void bucket_scan_kernel(const int* __restrict__ gcur,
                                                          int* __restrict__ bbase) {
  __shared__ int s[128];
  int tid = threadIdx.x;
  int c = (tid < NBUCK) ? (gcur[tid] - tid * BSTRIDE) : 0;
  s[tid] = c;
  __syncthreads();
  for (int off = 1; off < 128; off <<= 1) {
    int v = (tid >= off) ? s[tid - off] : 0;
    __syncthreads();
    s[tid] += v;
    __syncthreads();
  }
  if (tid < NBUCK) bbase[tid] = s[tid] - c;
}

// pass2: per-bucket dst-sort in LDS; derives degree -> dis, offs; emits u16 CSR.
__global__ __launch_bounds__(1024) void pass2_kernel(const unsigned int* __restrict__ bucketBuf,
                                                     const int* __restrict__ gcur,
                                                     const int* __restrict__ bbase,
                                                     int* __restrict__ offs,
                                                     float* __restrict__ dis,
                                                     unsigned short* __restrict__ csr) {
  __shared__ unsigned int raw[BSTRIDE];      // 40 KB
  __shared__ unsigned short sorted[BSTRIDE]; // 20 KB
  __shared__ int h[512], pos[512], cur[512];

  int b = blockIdx.x;
  int tid = threadIdx.x;
  int nStart = b << BSHIFT;
  int cnt = gcur[b] - b * BSTRIDE;
  if (cnt > BSTRIDE) cnt = BSTRIDE;
  int eStart = bbase[b];

  for (int i = tid; i < cnt; i += 1024) raw[i] = bucketBuf[(size_t)b * BSTRIDE + i];
  if (tid < 512) h[tid] = 0;
  __syncthreads();

  for (int i = tid; i < cnt; i += 1024) atomicAdd(&h[(raw[i] >> 16) - nStart], 1);
  __syncthreads();

  if (tid < 512) pos[tid] = h[tid];
  __syncthreads();
  #pragma unroll
  for (int off = 1; off < 512; off <<= 1) {
    int v = 0;
    if (tid < 512 && tid >= off) v = pos[tid - off];
    __syncthreads();
    if (tid < 512) pos[tid] += v;
    __syncthreads();
  }
  if (tid < 512) {
    int ex = pos[tid] - h[tid];
    cur[tid] = ex;
    int n = nStart + tid;
    if (n < NN) {
      offs[n] = eStart + ex;
      dis[n] = rsqrtf((float)h[tid] + 1.0f);
    }
  }
  if (b == NBUCK - 1 && tid == 0) offs[NN] = eStart + cnt;
  __syncthreads();

  for (int i = tid; i < cnt; i += 1024) {
    unsigned int r = raw[i];
    int d = (int)(r >> 16) - nStart;
    int p = atomicAdd(&cur[d], 1);
    sorted[p] = (unsigned short)(r & 0xFFFFu);
  }
  __syncthreads();

  for (int i = tid; i < cnt; i += 1024) csr[eStart + i] = sorted[i];
}

// ---------------- W fragment prep: split to bf16 hi/lo in MFMA lane order ----------
// wf layout: [ct(8)][ks(4)][plane(2: hi,lo)][lane(64)][j(8)] bf16
// element (k, c): k = ks*32 + (lane>>4)*8 + j ; c = ct*16 + (lane&15)

__global__ __launch_bounds__(256) void prep_w_kernel(const float* __restrict__ W,
                                                     unsigned short* __restrict__ wf) {
  int i = blockIdx.x * 256 + threadIdx.x;  // 0..16383
  if (i >= 16384) return;
  int j = i & 7, l = (i >> 3) & 63, ks = (i >> 9) & 3, ct = i >> 11;
  int k = ks * 32 + (l >> 4) * 8 + j;
  int c = ct * 16 + (l & 15);
  float w = W[k * 128 + c];
  unsigned int bb = __float_as_uint(w);
  unsigned int bh = bb & 0xFFFF0000u;
  float r = w - __uint_as_float(bh);    // exact
  int base = (((ct * 4 + ks) * 2 + 0) * 64 + l) * 8 + j;
  wf[base] = (unsigned short)(bh >> 16);
  wf[base + 512] = f2bf(r);             // lo plane
}

// ---------------- MFMA GEMM: Hb(bf16) = act(A) @ W via 3-term bf16 split ----------
// block = 256 thr = 4 waves; 32 rows/wave => 128 rows/block.
// B-fragment ds_reads amortized over 2 row-groups (192 MFMA per 64 ds_read_b128).

__global__ __launch_bounds__(256) void gemm_mfma_kernel(const float* __restrict__ A,
                                                        const unsigned short* __restrict__ wf,
                                                        unsigned short* __restrict__ Hb,
                                                        int applyRelu) {
  __shared__ unsigned short ldsW[32768];  // 64 KB
  int tid = threadIdx.x;
  {
    const uint4* src = reinterpret_cast<const uint4*>(wf);
    uint4* dst = reinterpret_cast<uint4*>(ldsW);
    #pragma unroll
    for (int i = 0; i < 16; ++i) dst[tid + i * 256] = src[tid + i * 256];
  }
  __syncthreads();

  int w = tid >> 6, lane = tid & 63;
  int rowbase = blockIdx.x * 128 + w * 32;
  int kgrp = lane >> 4;
  int r0 = rowbase + (lane & 15);
  int r1 = r0 + 16;
  int a0 = (r0 < NN) ? r0 : 0;
  int a1 = (r1 < NN) ? r1 : 0;

  f32x4 acc0[8], acc1[8];
  #pragma unroll
  for (int ct = 0; ct < 8; ++ct) {
    f32x4 z = {0.f, 0.f, 0.f, 0.f};
    acc0[ct] = z; acc1[ct] = z;
  }

  #pragma unroll
  for (int ks = 0; ks < 4; ++ks) {
    bf16x8 ahi0, alo0, ahi1, alo1;
    {
      const float* ap = A + (size_t)a0 * FD + ks * 32 + kgrp * 8;
      float4 v0 = *reinterpret_cast<const float4*>(ap);
      float4 v1 = *reinterpret_cast<const float4*>(ap + 4);
      float a[8] = {v0.x, v0.y, v0.z, v0.w, v1.x, v1.y, v1.z, v1.w};
      #pragma unroll
      for (int j = 0; j < 8; ++j) {
        float v = a[j];
        if (applyRelu) v = fmaxf(v, 0.f);
        unsigned int bb = __float_as_uint(v);
        unsigned int bh = bb & 0xFFFF0000u;
        float r = v - __uint_as_float(bh);
        ahi0[j] = (short)(bh >> 16);
        alo0[j] = (short)f2bf(r);
      }
    }
    {
      const float* ap = A + (size_t)a1 * FD + ks * 32 + kgrp * 8;
      float4 v0 = *reinterpret_cast<const float4*>(ap);
      float4 v1 = *reinterpret_cast<const float4*>(ap + 4);
      float a[8] = {v0.x, v0.y, v0.z, v0.w, v1.x, v1.y, v1.z, v1.w};
      #pragma unroll
      for (int j = 0; j < 8; ++j) {
        float v = a[j];
        if (applyRelu) v = fmaxf(v, 0.f);
        unsigned int bb = __float_as_uint(v);
        unsigned int bh = bb & 0xFFFF0000u;
        float r = v - __uint_as_float(bh);
        ahi1[j] = (short)(bh >> 16);
        alo1[j] = (short)f2bf(r);
      }
    }
    #pragma unroll
    for (int ct = 0; ct < 8; ++ct) {
      int off = (((ct * 4 + ks) * 2) * 64 + lane) * 8;
      bf16x8 bhi = *reinterpret_cast<const bf16x8*>(&ldsW[off]);
      bf16x8 blo = *reinterpret_cast<const bf16x8*>(&ldsW[off + 512]);
      acc0[ct] = __builtin_amdgcn_mfma_f32_16x16x32_bf16(ahi0, bhi, acc0[ct], 0, 0, 0);
      acc1[ct] = __builtin_amdgcn_mfma_f32_16x16x32_bf16(ahi1, bhi, acc1[ct], 0, 0, 0);
      acc0[ct] = __builtin_amdgcn_mfma_f32_16x16x32_bf16(alo0, bhi, acc0[ct], 0, 0, 0);
      acc1[ct] = __builtin_amdgcn_mfma_f32_16x16x32_bf16(alo1, bhi, acc1[ct], 0, 0, 0);
      acc0[ct] = __builtin_amdgcn_mfma_f32_16x16x32_bf16(ahi0, blo, acc0[ct], 0, 0, 0);
      acc1[ct] = __builtin_amdgcn_mfma_f32_16x16x32_bf16(ahi1, blo, acc1[ct], 0, 0, 0);
    }
  }

  // C layout: col = lane&15 (+16*ct), row = base + (lane>>4)*4 + i
  int ccol = lane & 15;
  #pragma unroll
  for (int g = 0; g < 2; ++g) {
    int crow0 = rowbase + g * 16 + kgrp * 4;
    #pragma unroll
    for (int i = 0; i < 4; ++i) {
      int r = crow0 + i;
      if (r < NN) {
        #pragma unroll
        for (int ct = 0; ct < 8; ++ct) {
          float v = g ? acc1[ct][i] : acc0[ct][i];
          Hb[(size_t)r * FD + ct * 16 + ccol] = f2bf(v);
        }
      }
    }
  }
}

// ---------------- fused aggregation ----------------
// AGG[n][c] = b[c] + dis[n]^2 * H[n][c] + sum_e dis[src_e]*dis[n] * H[src_e][c]
// Wave per node; halves take alternate edges; fully-predicated 8-edge chunks
// keep 4 gathers in flight per lane even in the tail.

__global__ __launch_bounds__(256) void agg_edge_kernel(const int* __restrict__ offs,
                                                       const unsigned short* __restrict__ csr,
                                                       const float* __restrict__ dis,
                                                       const unsigned short* __restrict__ Hb,
                                                       const float* __restrict__ b,
                                                       float* __restrict__ AGG) {
  int node = blockIdx.x * 4 + (threadIdx.x >> 6);
  if (node >= NN) return;
  node = __builtin_amdgcn_readfirstlane(node);
  int lane = threadIdx.x & 63;
  int half = lane >> 5;
  int ch = (lane & 31) * 4;
  int beg = offs[node], end = offs[node + 1];
  float disn = dis[node];

  float4 accA, accB, accC, accD;
  accB = make_float4(0.f, 0.f, 0.f, 0.f);
  accC = accB; accD = accB;
  {
    float d2 = disn * disn;
    if (half == 0) {
      float4 bb = reinterpret_cast<const float4*>(b)[lane & 31];
      ushort4 hn = *reinterpret_cast<const ushort4*>(&Hb[(size_t)node * FD + ch]);
      accA = make_float4(bb.x + d2 * bf2f(hn.x), bb.y + d2 * bf2f(hn.y),
                         bb.z + d2 * bf2f(hn.z), bb.w + d2 * bf2f(hn.w));
    } else {
      accA = make_float4(0.f, 0.f, 0.f, 0.f);
    }
  }

  int last = end - 1;
  for (int j = beg; j < end; j += 8) {
    int e0 = j + 0 + half, e1 = j + 2 + half, e2 = j + 4 + half, e3 = j + 6 + half;
    int i0 = (e0 <= last) ? e0 : last;
    int i1 = (e1 <= last) ? e1 : last;
    int i2 = (e2 <= last) ? e2 : last;
    int i3 = (e3 <= last) ? e3 : last;
    int s0 = csr[i0], s1 = csr[i1], s2 = csr[i2], s3 = csr[i3];
    float c0 = (e0 <= last) ? dis[s0] * disn : 0.f;
    float c1 = (e1 <= last) ? dis[s1] * disn : 0.f;
    float c2 = (e2 <= last) ? dis[s2] * disn : 0.f;
    float c3 = (e3 <= last) ? dis[s3] * disn : 0.f;
    ushort4 h0 = *reinterpret_cast<const ushort4*>(&Hb[(size_t)s0 * FD + ch]);
    ushort4 h1 = *reinterpret_cast<const ushort4*>(&Hb[(size_t)s1 * FD + ch]);
    ushort4 h2 = *reinterpret_cast<const ushort4*>(&Hb[(size_t)s2 * FD + ch]);
    ushort4 h3 = *reinterpret_cast<const ushort4*>(&Hb[(size_t)s3 * FD + ch]);
    accA.x += c0 * bf2f(h0.x); accA.y += c0 * bf2f(h0.y);
    accA.z += c0 * bf2f(h0.z); accA.w += c0 * bf2f(h0.w);
    accB.x += c1 * bf2f(h1.x); accB.y += c1 * bf2f(h1.y);
    accB.z += c1 * bf2f(h1.z); accB.w += c1 * bf2f(h1.w);
    accC.x += c2 * bf2f(h2.x); accC.y += c2 * bf2f(h2.y);
    accC.z += c2 * bf2f(h2.z); accC.w += c2 * bf2f(h2.w);
    accD.x += c3 * bf2f(h3.x); accD.y += c3 * bf2f(h3.y);
    accD.z += c3 * bf2f(h3.z); accD.w += c3 * bf2f(h3.w);
  }
  accA.x += accB.x + accC.x + accD.x;
  accA.y += accB.y + accC.y + accD.y;
  accA.z += accB.z + accC.z + accD.z;
  accA.w += accB.w + accC.w + accD.w;

  accA.x += __shfl_xor(accA.x, 32, 64);
  accA.y += __shfl_xor(accA.y, 32, 64);
  accA.z += __shfl_xor(accA.z, 32, 64);
  accA.w += __shfl_xor(accA.w, 32, 64);

  if (half == 0) {
    reinterpret_cast<float4*>(AGG)[(size_t)node * 32 + (lane & 31)] = accA;
  }
}

// ---------------- fused pooling + classifier ----------------

__device__ __forceinline__ int lower_bound(const int* __restrict__ b, int n, int key) {
  int lo = 0, hi = n;
  while (lo < hi) {
    int m = (lo + hi) >> 1;
    if (b[m] < key) lo = m + 1; else hi = m;
  }
  return lo;
}

__global__ __launch_bounds__(256) void pool_final_kernel(const float* __restrict__ AGG,
                                                         const int* __restrict__ batch,
                                                         const float* __restrict__ Wl,
                                                         const float* __restrict__ bl,
                                                         float* __restrict__ out) {
  int g = blockIdx.x;
  int tid = threadIdx.x;
  int lane = tid & 63, w = tid >> 6;
  int start = lower_bound(batch, NN, g);
  int end = lower_bound(batch, NN, g + 1);

  const float2* AGG2 = reinterpret_cast<const float2*>(AGG);
  float2 acc = make_float2(0.f, 0.f);
  for (int n = start + w; n < end; n += 4) {
    float2 v = AGG2[(size_t)n * 64 + lane];
    acc.x += v.x; acc.y += v.y;
  }
  __shared__ float red[4][FD];
  red[w][lane * 2 + 0] = acc.x;
  red[w][lane * 2 + 1] = acc.y;
  __syncthreads();
  if (w == 0) {
    float px = red[0][lane * 2] + red[1][lane * 2] + red[2][lane * 2] + red[3][lane * 2];
    float py = red[0][lane * 2 + 1] + red[1][lane * 2 + 1] + red[2][lane * 2 + 1] + red[3][lane * 2 + 1];
    float inv = 1.0f / fmaxf((float)(end - start), 1.0f);
    px *= inv; py *= inv;
    float pc[NC];
    #pragma unroll
    for (int c = 0; c < NC; ++c)
      pc[c] = px * Wl[(2 * lane) * NC + c] + py * Wl[(2 * lane + 1) * NC + c];
    #pragma unroll
    for (int off = 32; off > 0; off >>= 1) {
      #pragma unroll
      for (int c = 0; c < NC; ++c) pc[c] += __shfl_down(pc[c], off, 64);
    }
    if (lane == 0) {
      #pragma unroll
      for (int c = 0; c < NC; ++c) out[g * NC + c] = pc[c] + bl[c];
    }
  }
}

// ---------------- launch ----------------

extern "C" void kernel_launch(void* const* d_in, const int* in_sizes, int n_in,
                              void* d_out, int out_size, void* d_ws, size_t ws_size,
                              hipStream_t stream) {
  const float* x       = (const float*)d_in[0];
  const int* ei        = (const int*)d_in[1];    // int32 on device
  const int* batch     = (const int*)d_in[2];    // int32 on device
  const float* W1 = (const float*)d_in[3];
  const float* b1 = (const float*)d_in[4];
  const float* W2 = (const float*)d_in[5];
  const float* b2 = (const float*)d_in[6];
  const float* W3 = (const float*)d_in[7];
  const float* b3 = (const float*)d_in[8];
  const float* Wl = (const float*)d_in[9];
  const float* bl = (const float*)d_in[10];
  float* out = (float*)d_out;

  char* ws = (char*)d_ws;
  size_t o = 0;
  auto alloc = [&](size_t bytes) {
    void* p = ws + o;
    o += bytes;
    o = (o + 255) & ~(size_t)255;
    return p;
  };
  int*   offs   = (int*)  alloc((size_t)(NN + 1) * 4);
  float* dis    = (float*)alloc((size_t)NN * 4);
  int*   gcur   = (int*)  alloc((size_t)NBUCK * 4);
  int*   bbase  = (int*)  alloc((size_t)NBUCK * 4);
  unsigned int* bucketBuf = (unsigned int*)alloc((size_t)NBUCK * BSTRIDE * 4);
  unsigned short* csr = (unsigned short*)alloc((size_t)NE * 2);
  unsigned short* hb  = (unsigned short*)alloc((size_t)NN * FD * 2);
  float* agg    = (float*)alloc((size_t)NN * FD * 4);
  unsigned short* wf1 = (unsigned short*)alloc((size_t)2 * FD * FD * 2);
  unsigned short* wf2 = (unsigned short*)alloc((size_t)2 * FD * FD * 2);
  unsigned short* wf3 = (unsigned short*)alloc((size_t)2 * FD * FD * 2);

  init_kernel<<<1, 128, 0, stream>>>(gcur);
  pass1_kernel<<<P1_BLOCKS, 1024, 0, stream>>>(ei, gcur, bucketBuf);
  bucket_scan_kernel<<<1, 128, 0, stream>>>(gcur, bbase);
  pass2_kernel<<<NBUCK, 1024, 0, stream>>>(bucketBuf, gcur, bbase, offs, dis, csr);
  prep_w_kernel<<<64, 256, 0, stream>>>(W1, wf1);
  prep_w_kernel<<<64, 256, 0, stream>>>(W2, wf2);
  prep_w_kernel<<<64, 256, 0, stream>>>(W3, wf3);

  int gemmGrid = (NN + 127) / 128;
  int nodeGrid = (NN + 3) / 4;

  // layer 1
  gemm_mfma_kernel<<<gemmGrid, 256, 0, stream>>>(x, wf1, hb, 0);
  agg_edge_kernel<<<nodeGrid, 256, 0, stream>>>(offs, csr, dis, hb, b1, agg);
  // layer 2
  gemm_mfma_kernel<<<gemmGrid, 256, 0, stream>>>(agg, wf2, hb, 1);
  agg_edge_kernel<<<nodeGrid, 256, 0, stream>>>(offs, csr, dis, hb, b2, agg);
  // layer 3
  gemm_mfma_kernel<<<gemmGrid, 256, 0, stream>>>(agg, wf3, hb, 1);
  agg_edge_kernel<<<nodeGrid, 256, 0, stream>>>(offs, csr, dis, hb, b3, agg);

  pool_final_kernel<<<NG, 256, 0, stream>>>(agg, batch, Wl, bl, out);
}

// Round 8
// 197.349 us; speedup vs baseline: 1.1561x; 1.1561x over previous
//
#include <hip/hip_runtime.h>

#define NN 50000
#define NE 800000
#define FD 128
#define NG 512
#define NC 10

// bucketed CSR build
#define NBUCK 98            // ceil(50000/512)
#define BSHIFT 9            // 512 nodes per bucket
#define BSTRIDE 10240       // slots per bucket region (mean 8192, sd ~90)
#define P1_EPB 4096         // edges per pass1 block
#define P1_BLOCKS ((NE + P1_EPB - 1) / P1_EPB)  // 196

typedef __attribute__((ext_vector_type(8))) short bf16x8;
typedef __attribute__((ext_vector_type(4))) float f32x4;

// ---------------- bf16 helpers ----------------

__device__ __forceinline__ float bf2f(unsigned short u) {
  return __uint_as_float(((unsigned int)u) << 16);
}
__device__ __forceinline__ unsigned short f2bf(float f) {
  unsigned int b = __float_as_uint(f);
  b += 0x7FFF + ((b >> 16) & 1);   // round-to-nearest-even
  return (unsigned short)(b >> 16);
}
__device__ __forceinline__ float blo(unsigned int u) {
  return __uint_as_float(u << 16);
}
__device__ __forceinline__ float bhi(unsigned int u) {
  return __uint_as_float(u & 0xFFFF0000u);
}

// ---------------- setup ----------------

__global__ __launch_bounds__(128) void init_kernel(int* __restrict__ gcursor) {
  int i = threadIdx.x;
  if (i < NBUCK) gcursor[i] = i * BSTRIDE;
}

// pass1: histogram -> per-block bucket reservation -> direct scatter.
// Writes land in block-private contiguous runs (no cross-XCD line sharing).
__global__ __launch_bounds__(1024) void pass1_kernel(const int* __restrict__ ei,
                                                     int* __restrict__ gcursor,
                                                     unsigned int* __restrict__ bucketBuf) {
  __shared__ int bh[NBUCK];
  __shared__ int gbase[NBUCK];
  __shared__ int bcur[NBUCK];

  int tid = threadIdx.x;
  int e0 = blockIdx.x * P1_EPB;
  int ne = NE - e0; if (ne > P1_EPB) ne = P1_EPB;

  if (tid < NBUCK) bh[tid] = 0;
  __syncthreads();

  for (int i = tid; i < ne; i += 1024) {
    int d = ei[NE + e0 + i];
    atomicAdd(&bh[d >> BSHIFT], 1);
  }
  __syncthreads();

  if (tid < NBUCK) {
    bcur[tid] = 0;
    gbase[tid] = (bh[tid] > 0) ? atomicAdd(&gcursor[tid], bh[tid]) : 0;
  }
  __syncthreads();

  for (int i = tid; i < ne; i += 1024) {
    int s = ei[e0 + i];
    int d = ei[NE + e0 + i];
    int b = d >> BSHIFT;
    int p = atomicAdd(&bcur[b], 1);
    bucketBuf[gbase[b] + p] = (unsigned int)s | ((unsigned int)d << 16);
  }
}

// exclusive scan of 98 bucket totals -> bbase
__global__ __launch_bounds__(128) void bucket_scan_kernel(const int* __restrict__ gcur,
                                                          int* __restrict__ bbase) {
  __shared__ int s[128];
  int tid = threadIdx.x;
  int c = (tid < NBUCK) ? (gcur[tid] - tid * BSTRIDE) : 0;
  s[tid] = c;
  __syncthreads();
  for (int off = 1; off < 128; off <<= 1) {
    int v = (tid >= off) ? s[tid - off] : 0;
    __syncthreads();
    s[tid] += v;
    __syncthreads();
  }
  if (tid < NBUCK) bbase[tid] = s[tid] - c;
}

// pass2: per-bucket dst-sort in LDS; derives degree -> dis, offs; emits u16 CSR.
__global__ __launch_bounds__(1024) void pass2_kernel(const unsigned int* __restrict__ bucketBuf,
                                                     const int* __restrict__ gcur,
                                                     const int* __restrict__ bbase,
                                                     int* __restrict__ offs,
                                                     float* __restrict__ dis,
                                                     unsigned short* __restrict__ csr) {
  __shared__ unsigned int raw[BSTRIDE];      // 40 KB
  __shared__ unsigned short sorted[BSTRIDE]; // 20 KB
  __shared__ int h[512], pos[512], cur[512];

  int b = blockIdx.x;
  int tid = threadIdx.x;
  int nStart = b << BSHIFT;
  int cnt = gcur[b] - b * BSTRIDE;
  if (cnt > BSTRIDE) cnt = BSTRIDE;
  int eStart = bbase[b];

  for (int i = tid; i < cnt; i += 1024) raw[i] = bucketBuf[(size_t)b * BSTRIDE + i];
  if (tid < 512) h[tid] = 0;
  __syncthreads();

  for (int i = tid; i < cnt; i += 1024) atomicAdd(&h[(raw[i] >> 16) - nStart], 1);
  __syncthreads();

  if (tid < 512) pos[tid] = h[tid];
  __syncthreads();
  #pragma unroll
  for (int off = 1; off < 512; off <<= 1) {
    int v = 0;
    if (tid < 512 && tid >= off) v = pos[tid - off];
    __syncthreads();
    if (tid < 512) pos[tid] += v;
    __syncthreads();
  }
  if (tid < 512) {
    int ex = pos[tid] - h[tid];
    cur[tid] = ex;
    int n = nStart + tid;
    if (n < NN) {
      offs[n] = eStart + ex;
      dis[n] = rsqrtf((float)h[tid] + 1.0f);
    }
  }
  if (b == NBUCK - 1 && tid == 0) offs[NN] = eStart + cnt;
  __syncthreads();

  for (int i = tid; i < cnt; i += 1024) {
    unsigned int r = raw[i];
    int d = (int)(r >> 16) - nStart;
    int p = atomicAdd(&cur[d], 1);
    sorted[p] = (unsigned short)(r & 0xFFFFu);
  }
  __syncthreads();

  for (int i = tid; i < cnt; i += 1024) csr[eStart + i] = sorted[i];
}

// ---------------- W fragment prep: split to bf16 hi/lo in MFMA lane order ----------

__global__ __launch_bounds__(256) void prep_w_kernel(const float* __restrict__ W,
                                                     unsigned short* __restrict__ wf) {
  int i = blockIdx.x * 256 + threadIdx.x;  // 0..16383
  if (i >= 16384) return;
  int j = i & 7, l = (i >> 3) & 63, ks = (i >> 9) & 3, ct = i >> 11;
  int k = ks * 32 + (l >> 4) * 8 + j;
  int c = ct * 16 + (l & 15);
  float w = W[k * 128 + c];
  unsigned int bb = __float_as_uint(w);
  unsigned int bh = bb & 0xFFFF0000u;
  float r = w - __uint_as_float(bh);    // exact
  int base = (((ct * 4 + ks) * 2 + 0) * 64 + l) * 8 + j;
  wf[base] = (unsigned short)(bh >> 16);
  wf[base + 512] = f2bf(r);             // lo plane
}

// ---------------- MFMA GEMM: Hb(bf16) = act(A) @ W via 3-term bf16 split ----------
// block = 256 thr = 4 waves; 32 rows/wave => 128 rows/block.

__global__ __launch_bounds__(256) void gemm_mfma_kernel(const float* __restrict__ A,
                                                        const unsigned short* __restrict__ wf,
                                                        unsigned short* __restrict__ Hb,
                                                        int applyRelu) {
  __shared__ unsigned short ldsW[32768];  // 64 KB
  int tid = threadIdx.x;
  {
    const uint4* src = reinterpret_cast<const uint4*>(wf);
    uint4* dst = reinterpret_cast<uint4*>(ldsW);
    #pragma unroll
    for (int i = 0; i < 16; ++i) dst[tid + i * 256] = src[tid + i * 256];
  }
  __syncthreads();

  int w = tid >> 6, lane = tid & 63;
  int rowbase = blockIdx.x * 128 + w * 32;
  int kgrp = lane >> 4;
  int r0 = rowbase + (lane & 15);
  int r1 = r0 + 16;
  int a0 = (r0 < NN) ? r0 : 0;
  int a1 = (r1 < NN) ? r1 : 0;

  f32x4 acc0[8], acc1[8];
  #pragma unroll
  for (int ct = 0; ct < 8; ++ct) {
    f32x4 z = {0.f, 0.f, 0.f, 0.f};
    acc0[ct] = z; acc1[ct] = z;
  }

  #pragma unroll
  for (int ks = 0; ks < 4; ++ks) {
    bf16x8 ahi0, alo0, ahi1, alo1;
    {
      const float* ap = A + (size_t)a0 * FD + ks * 32 + kgrp * 8;
      float4 v0 = *reinterpret_cast<const float4*>(ap);
      float4 v1 = *reinterpret_cast<const float4*>(ap + 4);
      float a[8] = {v0.x, v0.y, v0.z, v0.w, v1.x, v1.y, v1.z, v1.w};
      #pragma unroll
      for (int j = 0; j < 8; ++j) {
        float v = a[j];
        if (applyRelu) v = fmaxf(v, 0.f);
        unsigned int bb = __float_as_uint(v);
        unsigned int bh = bb & 0xFFFF0000u;
        float r = v - __uint_as_float(bh);
        ahi0[j] = (short)(bh >> 16);
        alo0[j] = (short)f2bf(r);
      }
    }
    {
      const float* ap = A + (size_t)a1 * FD + ks * 32 + kgrp * 8;
      float4 v0 = *reinterpret_cast<const float4*>(ap);
      float4 v1 = *reinterpret_cast<const float4*>(ap + 4);
      float a[8] = {v0.x, v0.y, v0.z, v0.w, v1.x, v1.y, v1.z, v1.w};
      #pragma unroll
      for (int j = 0; j < 8; ++j) {
        float v = a[j];
        if (applyRelu) v = fmaxf(v, 0.f);
        unsigned int bb = __float_as_uint(v);
        unsigned int bh = bb & 0xFFFF0000u;
        float r = v - __uint_as_float(bh);
        ahi1[j] = (short)(bh >> 16);
        alo1[j] = (short)f2bf(r);
      }
    }
    #pragma unroll
    for (int ct = 0; ct < 8; ++ct) {
      int off = (((ct * 4 + ks) * 2) * 64 + lane) * 8;
      bf16x8 bhiV = *reinterpret_cast<const bf16x8*>(&ldsW[off]);
      bf16x8 bloV = *reinterpret_cast<const bf16x8*>(&ldsW[off + 512]);
      acc0[ct] = __builtin_amdgcn_mfma_f32_16x16x32_bf16(ahi0, bhiV, acc0[ct], 0, 0, 0);
      acc1[ct] = __builtin_amdgcn_mfma_f32_16x16x32_bf16(ahi1, bhiV, acc1[ct], 0, 0, 0);
      acc0[ct] = __builtin_amdgcn_mfma_f32_16x16x32_bf16(alo0, bhiV, acc0[ct], 0, 0, 0);
      acc1[ct] = __builtin_amdgcn_mfma_f32_16x16x32_bf16(alo1, bhiV, acc1[ct], 0, 0, 0);
      acc0[ct] = __builtin_amdgcn_mfma_f32_16x16x32_bf16(ahi0, bloV, acc0[ct], 0, 0, 0);
      acc1[ct] = __builtin_amdgcn_mfma_f32_16x16x32_bf16(ahi1, bloV, acc1[ct], 0, 0, 0);
    }
  }

  int ccol = lane & 15;
  #pragma unroll
  for (int g = 0; g < 2; ++g) {
    int crow0 = rowbase + g * 16 + kgrp * 4;
    #pragma unroll
    for (int i = 0; i < 4; ++i) {
      int r = crow0 + i;
      if (r < NN) {
        #pragma unroll
        for (int ct = 0; ct < 8; ++ct) {
          float v = g ? acc1[ct][i] : acc0[ct][i];
          Hb[(size_t)r * FD + ct * 16 + ccol] = f2bf(v);
        }
      }
    }
  }
}

// ---------------- fused aggregation (quarter-wave, 16B gathers) ----------------
// AGG[n][c] = b[c] + dis[n]^2 * H[n][c] + sum_e dis[src_e]*dis[n] * H[src_e][c]
// Wave per node. Quarter q (16 lanes) handles edges j+q, j+q+4, j+q+8, j+q+12;
// each lane loads uint4 (8 bf16 ch) -> 16 lanes cover the full 256B row.
// 4 independent 16B gathers in flight per lane; combine via shfl_xor(16,32).

__global__ __launch_bounds__(256) void agg_edge_kernel(const int* __restrict__ offs,
                                                       const unsigned short* __restrict__ csr,
                                                       const float* __restrict__ dis,
                                                       const unsigned short* __restrict__ Hb,
                                                       const float* __restrict__ b,
                                                       float* __restrict__ AGG) {
  int node = blockIdx.x * 4 + (threadIdx.x >> 6);
  if (node >= NN) return;
  node = __builtin_amdgcn_readfirstlane(node);
  int lane = threadIdx.x & 63;
  int q = lane >> 4;           // quarter 0..3
  int ch = (lane & 15) * 8;    // 8 channels per lane
  int beg = offs[node], end = offs[node + 1];
  float disn = dis[node];

  float accP[8], accQ[8];
  #pragma unroll
  for (int k = 0; k < 8; ++k) { accP[k] = 0.f; accQ[k] = 0.f; }

  if (q == 0) {
    float d2 = disn * disn;
    float4 b0 = *reinterpret_cast<const float4*>(&b[ch]);
    float4 b1 = *reinterpret_cast<const float4*>(&b[ch + 4]);
    uint4 hn = *reinterpret_cast<const uint4*>(&Hb[(size_t)node * FD + ch]);
    accP[0] = b0.x + d2 * blo(hn.x); accP[1] = b0.y + d2 * bhi(hn.x);
    accP[2] = b0.z + d2 * blo(hn.y); accP[3] = b0.w + d2 * bhi(hn.y);
    accP[4] = b1.x + d2 * blo(hn.z); accP[5] = b1.y + d2 * bhi(hn.z);
    accP[6] = b1.z + d2 * blo(hn.w); accP[7] = b1.w + d2 * bhi(hn.w);
  }

  int last = end - 1;
  for (int j = beg; j < end; j += 16) {
    int e0 = j + q, e1 = j + q + 4, e2 = j + q + 8, e3 = j + q + 12;
    int i0 = (e0 <= last) ? e0 : last;
    int i1 = (e1 <= last) ? e1 : last;
    int i2 = (e2 <= last) ? e2 : last;
    int i3 = (e3 <= last) ? e3 : last;
    int s0 = csr[i0], s1 = csr[i1], s2 = csr[i2], s3 = csr[i3];
    float c0 = (e0 <= last) ? dis[s0] * disn : 0.f;
    float c1 = (e1 <= last) ? dis[s1] * disn : 0.f;
    float c2 = (e2 <= last) ? dis[s2] * disn : 0.f;
    float c3 = (e3 <= last) ? dis[s3] * disn : 0.f;
    uint4 h0 = *reinterpret_cast<const uint4*>(&Hb[(size_t)s0 * FD + ch]);
    uint4 h1 = *reinterpret_cast<const uint4*>(&Hb[(size_t)s1 * FD + ch]);
    uint4 h2 = *reinterpret_cast<const uint4*>(&Hb[(size_t)s2 * FD + ch]);
    uint4 h3 = *reinterpret_cast<const uint4*>(&Hb[(size_t)s3 * FD + ch]);
    accP[0] += c0 * blo(h0.x); accP[1] += c0 * bhi(h0.x);
    accP[2] += c0 * blo(h0.y); accP[3] += c0 * bhi(h0.y);
    accP[4] += c0 * blo(h0.z); accP[5] += c0 * bhi(h0.z);
    accP[6] += c0 * blo(h0.w); accP[7] += c0 * bhi(h0.w);
    accQ[0] += c1 * blo(h1.x); accQ[1] += c1 * bhi(h1.x);
    accQ[2] += c1 * blo(h1.y); accQ[3] += c1 * bhi(h1.y);
    accQ[4] += c1 * blo(h1.z); accQ[5] += c1 * bhi(h1.z);
    accQ[6] += c1 * blo(h1.w); accQ[7] += c1 * bhi(h1.w);
    accP[0] += c2 * blo(h2.x); accP[1] += c2 * bhi(h2.x);
    accP[2] += c2 * blo(h2.y); accP[3] += c2 * bhi(h2.y);
    accP[4] += c2 * blo(h2.z); accP[5] += c2 * bhi(h2.z);
    accP[6] += c2 * blo(h2.w); accP[7] += c2 * bhi(h2.w);
    accQ[0] += c3 * blo(h3.x); accQ[1] += c3 * bhi(h3.x);
    accQ[2] += c3 * blo(h3.y); accQ[3] += c3 * bhi(h3.y);
    accQ[4] += c3 * blo(h3.z); accQ[5] += c3 * bhi(h3.z);
    accQ[6] += c3 * blo(h3.w); accQ[7] += c3 * bhi(h3.w);
  }

  #pragma unroll
  for (int k = 0; k < 8; ++k) {
    float v = accP[k] + accQ[k];
    v += __shfl_xor(v, 16, 64);
    v += __shfl_xor(v, 32, 64);
    accP[k] = v;
  }

  if (q == 0) {
    float4 o0 = make_float4(accP[0], accP[1], accP[2], accP[3]);
    float4 o1 = make_float4(accP[4], accP[5], accP[6], accP[7]);
    *reinterpret_cast<float4*>(&AGG[(size_t)node * FD + ch]) = o0;
    *reinterpret_cast<float4*>(&AGG[(size_t)node * FD + ch + 4]) = o1;
  }
}

// ---------------- fused pooling + classifier ----------------

__device__ __forceinline__ int lower_bound(const int* __restrict__ b, int n, int key) {
  int lo = 0, hi = n;
  while (lo < hi) {
    int m = (lo + hi) >> 1;
    if (b[m] < key) lo = m + 1; else hi = m;
  }
  return lo;
}

__global__ __launch_bounds__(256) void pool_final_kernel(const float* __restrict__ AGG,
                                                         const int* __restrict__ batch,
                                                         const float* __restrict__ Wl,
                                                         const float* __restrict__ bl,
                                                         float* __restrict__ out) {
  int g = blockIdx.x;
  int tid = threadIdx.x;
  int lane = tid & 63, w = tid >> 6;
  int start = lower_bound(batch, NN, g);
  int end = lower_bound(batch, NN, g + 1);

  const float2* AGG2 = reinterpret_cast<const float2*>(AGG);
  float2 acc = make_float2(0.f, 0.f);
  for (int n = start + w; n < end; n += 4) {
    float2 v = AGG2[(size_t)n * 64 + lane];
    acc.x += v.x; acc.y += v.y;
  }
  __shared__ float red[4][FD];
  red[w][lane * 2 + 0] = acc.x;
  red[w][lane * 2 + 1] = acc.y;
  __syncthreads();
  if (w == 0) {
    float px = red[0][lane * 2] + red[1][lane * 2] + red[2][lane * 2] + red[3][lane * 2];
    float py = red[0][lane * 2 + 1] + red[1][lane * 2 + 1] + red[2][lane * 2 + 1] + red[3][lane * 2 + 1];
    float inv = 1.0f / fmaxf((float)(end - start), 1.0f);
    px *= inv; py *= inv;
    float pc[NC];
    #pragma unroll
    for (int c = 0; c < NC; ++c)
      pc[c] = px * Wl[(2 * lane) * NC + c] + py * Wl[(2 * lane + 1) * NC + c];
    #pragma unroll
    for (int off = 32; off > 0; off >>= 1) {
      #pragma unroll
      for (int c = 0; c < NC; ++c) pc[c] += __shfl_down(pc[c], off, 64);
    }
    if (lane == 0) {
      #pragma unroll
      for (int c = 0; c < NC; ++c) out[g * NC + c] = pc[c] + bl[c];
    }
  }
}

// ---------------- launch ----------------

extern "C" void kernel_launch(void* const* d_in, const int* in_sizes, int n_in,
                              void* d_out, int out_size, void* d_ws, size_t ws_size,
                              hipStream_t stream) {
  const float* x       = (const float*)d_in[0];
  const int* ei        = (const int*)d_in[1];    // int32 on device
  const int* batch     = (const int*)d_in[2];    // int32 on device
  const float* W1 = (const float*)d_in[3];
  const float* b1 = (const float*)d_in[4];
  const float* W2 = (const float*)d_in[5];
  const float* b2 = (const float*)d_in[6];
  const float* W3 = (const float*)d_in[7];
  const float* b3 = (const float*)d_in[8];
  const float* Wl = (const float*)d_in[9];
  const float* bl = (const float*)d_in[10];
  float* out = (float*)d_out;

  char* ws = (char*)d_ws;
  size_t o = 0;
  auto alloc = [&](size_t bytes) {
    void* p = ws + o;
    o += bytes;
    o = (o + 255) & ~(size_t)255;
    return p;
  };
  int*   offs   = (int*)  alloc((size_t)(NN + 1) * 4);
  float* dis    = (float*)alloc((size_t)NN * 4);
  int*   gcur   = (int*)  alloc((size_t)NBUCK * 4);
  int*   bbase  = (int*)  alloc((size_t)NBUCK * 4);
  unsigned int* bucketBuf = (unsigned int*)alloc((size_t)NBUCK * BSTRIDE * 4);
  unsigned short* csr = (unsigned short*)alloc((size_t)NE * 2);
  unsigned short* hb  = (unsigned short*)alloc((size_t)NN * FD * 2);
  float* agg    = (float*)alloc((size_t)NN * FD * 4);
  unsigned short* wf1 = (unsigned short*)alloc((size_t)2 * FD * FD * 2);
  unsigned short* wf2 = (unsigned short*)alloc((size_t)2 * FD * FD * 2);
  unsigned short* wf3 = (unsigned short*)alloc((size_t)2 * FD * FD * 2);

  init_kernel<<<1, 128, 0, stream>>>(gcur);
  pass1_kernel<<<P1_BLOCKS, 1024, 0, stream>>>(ei, gcur, bucketBuf);
  bucket_scan_kernel<<<1, 128, 0, stream>>>(gcur, bbase);
  pass2_kernel<<<NBUCK, 1024, 0, stream>>>(bucketBuf, gcur, bbase, offs, dis, csr);
  prep_w_kernel<<<64, 256, 0, stream>>>(W1, wf1);
  prep_w_kernel<<<64, 256, 0, stream>>>(W2, wf2);
  prep_w_kernel<<<64, 256, 0, stream>>>(W3, wf3);

  int gemmGrid = (NN + 127) / 128;
  int nodeGrid = (NN + 3) / 4;

  // layer 1
  gemm_mfma_kernel<<<gemmGrid, 256, 0, stream>>>(x, wf1, hb, 0);
  agg_edge_kernel<<<nodeGrid, 256, 0, stream>>>(offs, csr, dis, hb, b1, agg);
  // layer 2
  gemm_mfma_kernel<<<gemmGrid, 256, 0, stream>>>(agg, wf2, hb, 1);
  agg_edge_kernel<<<nodeGrid, 256, 0, stream>>>(offs, csr, dis, hb, b2, agg);
  // layer 3
  gemm_mfma_kernel<<<gemmGrid, 256, 0, stream>>>(agg, wf3, hb, 1);
  agg_edge_kernel<<<nodeGrid, 256, 0, stream>>>(offs, csr, dis, hb, b3, agg);

  pool_final_kernel<<<NG, 256, 0, stream>>>(agg, batch, Wl, bl, out);
}

// Round 9
// 180.593 us; speedup vs baseline: 1.2633x; 1.0928x over previous
//
#include <hip/hip_runtime.h>

#define NN 50000
#define NE 800000
#define FD 128
#define NG 512
#define NC 10

// bucketed CSR build
#define NBUCK 98            // ceil(50000/512)
#define BSHIFT 9            // 512 nodes per bucket
#define BSTRIDE 10240       // slots per bucket region (mean 8192, sd ~90)
#define P1_EPB 4096         // edges per pass1 block
#define P1_BLOCKS ((NE + P1_EPB - 1) / P1_EPB)  // 196

typedef __attribute__((ext_vector_type(8))) short bf16x8;
typedef __attribute__((ext_vector_type(4))) float f32x4;

// ---------------- bf16 helpers ----------------

__device__ __forceinline__ unsigned short f2bf(float f) {
  unsigned int b = __float_as_uint(f);
  b += 0x7FFF + ((b >> 16) & 1);   // round-to-nearest-even
  return (unsigned short)(b >> 16);
}
__device__ __forceinline__ float blo(unsigned int u) {
  return __uint_as_float(u << 16);
}
__device__ __forceinline__ float bhi(unsigned int u) {
  return __uint_as_float(u & 0xFFFF0000u);
}

// ---------------- setup ----------------

__global__ __launch_bounds__(128) void init_kernel(int* __restrict__ gcursor) {
  int i = threadIdx.x;
  if (i < NBUCK) gcursor[i] = i * BSTRIDE;
}

// pass1: histogram -> per-block bucket reservation -> direct scatter.
__global__ __launch_bounds__(1024) void pass1_kernel(const int* __restrict__ ei,
                                                     int* __restrict__ gcursor,
                                                     unsigned int* __restrict__ bucketBuf) {
  __shared__ int bh[NBUCK];
  __shared__ int gbase[NBUCK];
  __shared__ int bcur[NBUCK];

  int tid = threadIdx.x;
  int e0 = blockIdx.x * P1_EPB;
  int ne = NE - e0; if (ne > P1_EPB) ne = P1_EPB;

  if (tid < NBUCK) bh[tid] = 0;
  __syncthreads();

  for (int i = tid; i < ne; i += 1024) {
    int d = ei[NE + e0 + i];
    atomicAdd(&bh[d >> BSHIFT], 1);
  }
  __syncthreads();

  if (tid < NBUCK) {
    bcur[tid] = 0;
    gbase[tid] = (bh[tid] > 0) ? atomicAdd(&gcursor[tid], bh[tid]) : 0;
  }
  __syncthreads();

  for (int i = tid; i < ne; i += 1024) {
    int s = ei[e0 + i];
    int d = ei[NE + e0 + i];
    int b = d >> BSHIFT;
    int p = atomicAdd(&bcur[b], 1);
    bucketBuf[gbase[b] + p] = (unsigned int)s | ((unsigned int)d << 16);
  }
}

// exclusive scan of 98 bucket totals -> bbase
__global__ __launch_bounds__(128) void bucket_scan_kernel(const int* __restrict__ gcur,
                                                          int* __restrict__ bbase) {
  __shared__ int s[128];
  int tid = threadIdx.x;
  int c = (tid < NBUCK) ? (gcur[tid] - tid * BSTRIDE) : 0;
  s[tid] = c;
  __syncthreads();
  for (int off = 1; off < 128; off <<= 1) {
    int v = (tid >= off) ? s[tid - off] : 0;
    __syncthreads();
    s[tid] += v;
    __syncthreads();
  }
  if (tid < NBUCK) bbase[tid] = s[tid] - c;
}

// pass2: per-bucket dst-sort in LDS; derives degree -> dis, offs; emits u16 CSR.
__global__ __launch_bounds__(1024) void pass2_kernel(const unsigned int* __restrict__ bucketBuf,
                                                     const int* __restrict__ gcur,
                                                     const int* __restrict__ bbase,
                                                     int* __restrict__ offs,
                                                     float* __restrict__ dis,
                                                     unsigned short* __restrict__ csr) {
  __shared__ unsigned int raw[BSTRIDE];      // 40 KB
  __shared__ unsigned short sorted[BSTRIDE]; // 20 KB
  __shared__ int h[512], pos[512], cur[512];

  int b = blockIdx.x;
  int tid = threadIdx.x;
  int nStart = b << BSHIFT;
  int cnt = gcur[b] - b * BSTRIDE;
  if (cnt > BSTRIDE) cnt = BSTRIDE;
  int eStart = bbase[b];

  for (int i = tid; i < cnt; i += 1024) raw[i] = bucketBuf[(size_t)b * BSTRIDE + i];
  if (tid < 512) h[tid] = 0;
  __syncthreads();

  for (int i = tid; i < cnt; i += 1024) atomicAdd(&h[(raw[i] >> 16) - nStart], 1);
  __syncthreads();

  if (tid < 512) pos[tid] = h[tid];
  __syncthreads();
  #pragma unroll
  for (int off = 1; off < 512; off <<= 1) {
    int v = 0;
    if (tid < 512 && tid >= off) v = pos[tid - off];
    __syncthreads();
    if (tid < 512) pos[tid] += v;
    __syncthreads();
  }
  if (tid < 512) {
    int ex = pos[tid] - h[tid];
    cur[tid] = ex;
    int n = nStart + tid;
    if (n < NN) {
      offs[n] = eStart + ex;
      dis[n] = rsqrtf((float)h[tid] + 1.0f);
    }
  }
  if (b == NBUCK - 1 && tid == 0) offs[NN] = eStart + cnt;
  __syncthreads();

  for (int i = tid; i < cnt; i += 1024) {
    unsigned int r = raw[i];
    int d = (int)(r >> 16) - nStart;
    int p = atomicAdd(&cur[d], 1);
    sorted[p] = (unsigned short)(r & 0xFFFFu);
  }
  __syncthreads();

  for (int i = tid; i < cnt; i += 1024) csr[eStart + i] = sorted[i];
}

// ---------------- W fragment prep: split to bf16 hi/lo in MFMA lane order ----------
// wf layout: [ct(8)][ks(4)][plane(2: hi,lo)][lane(64)][j(8)] bf16
// element (k, c): k = ks*32 + (lane>>4)*8 + j ; c = ct*16 + (lane&15)

__global__ __launch_bounds__(256) void prep_w_kernel(const float* __restrict__ W,
                                                     unsigned short* __restrict__ wf) {
  int i = blockIdx.x * 256 + threadIdx.x;  // 0..16383
  if (i >= 16384) return;
  int j = i & 7, l = (i >> 3) & 63, ks = (i >> 9) & 3, ct = i >> 11;
  int k = ks * 32 + (l >> 4) * 8 + j;
  int c = ct * 16 + (l & 15);
  float w = W[k * 128 + c];
  unsigned int bb = __float_as_uint(w);
  unsigned int bh = bb & 0xFFFF0000u;
  float r = w - __uint_as_float(bh);    // exact
  int base = (((ct * 4 + ks) * 2 + 0) * 64 + l) * 8 + j;
  wf[base] = (unsigned short)(bh >> 16);
  wf[base + 512] = f2bf(r);             // lo plane
}

// ---------------- GEMM layer1: Hs(bf16) = dis * (x @ W), x fp32, 3-term ----------

__global__ __launch_bounds__(256) void gemm_f32_kernel(const float* __restrict__ A,
                                                       const unsigned short* __restrict__ wf,
                                                       const float* __restrict__ dis,
                                                       unsigned short* __restrict__ Hs) {
  __shared__ unsigned short ldsW[32768];  // 64 KB
  int tid = threadIdx.x;
  {
    const uint4* src = reinterpret_cast<const uint4*>(wf);
    uint4* dst = reinterpret_cast<uint4*>(ldsW);
    #pragma unroll
    for (int i = 0; i < 16; ++i) dst[tid + i * 256] = src[tid + i * 256];
  }
  __syncthreads();

  int w = tid >> 6, lane = tid & 63;
  int rowbase = blockIdx.x * 128 + w * 32;
  int kgrp = lane >> 4;
  int r0 = rowbase + (lane & 15);
  int r1 = r0 + 16;
  int a0 = (r0 < NN) ? r0 : 0;
  int a1 = (r1 < NN) ? r1 : 0;

  f32x4 acc0[8], acc1[8];
  #pragma unroll
  for (int ct = 0; ct < 8; ++ct) {
    f32x4 z = {0.f, 0.f, 0.f, 0.f};
    acc0[ct] = z; acc1[ct] = z;
  }

  #pragma unroll
  for (int ks = 0; ks < 4; ++ks) {
    bf16x8 ahi0, alo0, ahi1, alo1;
    {
      const float* ap = A + (size_t)a0 * FD + ks * 32 + kgrp * 8;
      float4 v0 = *reinterpret_cast<const float4*>(ap);
      float4 v1 = *reinterpret_cast<const float4*>(ap + 4);
      float a[8] = {v0.x, v0.y, v0.z, v0.w, v1.x, v1.y, v1.z, v1.w};
      #pragma unroll
      for (int j = 0; j < 8; ++j) {
        unsigned int bb = __float_as_uint(a[j]);
        unsigned int bh = bb & 0xFFFF0000u;
        float r = a[j] - __uint_as_float(bh);
        ahi0[j] = (short)(bh >> 16);
        alo0[j] = (short)f2bf(r);
      }
    }
    {
      const float* ap = A + (size_t)a1 * FD + ks * 32 + kgrp * 8;
      float4 v0 = *reinterpret_cast<const float4*>(ap);
      float4 v1 = *reinterpret_cast<const float4*>(ap + 4);
      float a[8] = {v0.x, v0.y, v0.z, v0.w, v1.x, v1.y, v1.z, v1.w};
      #pragma unroll
      for (int j = 0; j < 8; ++j) {
        unsigned int bb = __float_as_uint(a[j]);
        unsigned int bh = bb & 0xFFFF0000u;
        float r = a[j] - __uint_as_float(bh);
        ahi1[j] = (short)(bh >> 16);
        alo1[j] = (short)f2bf(r);
      }
    }
    #pragma unroll
    for (int ct = 0; ct < 8; ++ct) {
      int off = (((ct * 4 + ks) * 2) * 64 + lane) * 8;
      bf16x8 bhiV = *reinterpret_cast<const bf16x8*>(&ldsW[off]);
      bf16x8 bloV = *reinterpret_cast<const bf16x8*>(&ldsW[off + 512]);
      acc0[ct] = __builtin_amdgcn_mfma_f32_16x16x32_bf16(ahi0, bhiV, acc0[ct], 0, 0, 0);
      acc1[ct] = __builtin_amdgcn_mfma_f32_16x16x32_bf16(ahi1, bhiV, acc1[ct], 0, 0, 0);
      acc0[ct] = __builtin_amdgcn_mfma_f32_16x16x32_bf16(alo0, bhiV, acc0[ct], 0, 0, 0);
      acc1[ct] = __builtin_amdgcn_mfma_f32_16x16x32_bf16(alo1, bhiV, acc1[ct], 0, 0, 0);
      acc0[ct] = __builtin_amdgcn_mfma_f32_16x16x32_bf16(ahi0, bloV, acc0[ct], 0, 0, 0);
      acc1[ct] = __builtin_amdgcn_mfma_f32_16x16x32_bf16(ahi1, bloV, acc1[ct], 0, 0, 0);
    }
  }

  int ccol = lane & 15;
  #pragma unroll
  for (int g = 0; g < 2; ++g) {
    int crow0 = rowbase + g * 16 + kgrp * 4;
    #pragma unroll
    for (int i = 0; i < 4; ++i) {
      int r = crow0 + i;
      if (r < NN) {
        float dv = dis[r];
        #pragma unroll
        for (int ct = 0; ct < 8; ++ct) {
          float v = g ? acc1[ct][i] : acc0[ct][i];
          Hs[(size_t)r * FD + ct * 16 + ccol] = f2bf(dv * v);
        }
      }
    }
  }
}

// ---------------- GEMM layers 2/3: Hs(bf16) = dis * (relu(Ab) @ W), Ab bf16, 2-term --

__global__ __launch_bounds__(256) void gemm_bf16_kernel(const unsigned short* __restrict__ Ab,
                                                        const unsigned short* __restrict__ wf,
                                                        const float* __restrict__ dis,
                                                        unsigned short* __restrict__ Hs) {
  __shared__ unsigned short ldsW[32768];  // 64 KB
  int tid = threadIdx.x;
  {
    const uint4* src = reinterpret_cast<const uint4*>(wf);
    uint4* dst = reinterpret_cast<uint4*>(ldsW);
    #pragma unroll
    for (int i = 0; i < 16; ++i) dst[tid + i * 256] = src[tid + i * 256];
  }
  __syncthreads();

  int w = tid >> 6, lane = tid & 63;
  int rowbase = blockIdx.x * 128 + w * 32;
  int kgrp = lane >> 4;
  int r0 = rowbase + (lane & 15);
  int r1 = r0 + 16;
  int a0 = (r0 < NN) ? r0 : 0;
  int a1 = (r1 < NN) ? r1 : 0;

  f32x4 acc0[8], acc1[8];
  #pragma unroll
  for (int ct = 0; ct < 8; ++ct) {
    f32x4 z = {0.f, 0.f, 0.f, 0.f};
    acc0[ct] = z; acc1[ct] = z;
  }

  #pragma unroll
  for (int ks = 0; ks < 4; ++ks) {
    bf16x8 av0, av1;
    {
      uint4 u = *reinterpret_cast<const uint4*>(&Ab[(size_t)a0 * FD + ks * 32 + kgrp * 8]);
      unsigned int uu[4] = {u.x, u.y, u.z, u.w};
      #pragma unroll
      for (int p = 0; p < 4; ++p) {
        unsigned short lo16 = (unsigned short)(uu[p] & 0xFFFFu);
        unsigned short hi16 = (unsigned short)(uu[p] >> 16);
        av0[2 * p + 0] = (short)(((short)lo16 < 0) ? 0 : lo16);  // relu on bf16
        av0[2 * p + 1] = (short)(((short)hi16 < 0) ? 0 : hi16);
      }
    }
    {
      uint4 u = *reinterpret_cast<const uint4*>(&Ab[(size_t)a1 * FD + ks * 32 + kgrp * 8]);
      unsigned int uu[4] = {u.x, u.y, u.z, u.w};
      #pragma unroll
      for (int p = 0; p < 4; ++p) {
        unsigned short lo16 = (unsigned short)(uu[p] & 0xFFFFu);
        unsigned short hi16 = (unsigned short)(uu[p] >> 16);
        av1[2 * p + 0] = (short)(((short)lo16 < 0) ? 0 : lo16);
        av1[2 * p + 1] = (short)(((short)hi16 < 0) ? 0 : hi16);
      }
    }
    #pragma unroll
    for (int ct = 0; ct < 8; ++ct) {
      int off = (((ct * 4 + ks) * 2) * 64 + lane) * 8;
      bf16x8 bhiV = *reinterpret_cast<const bf16x8*>(&ldsW[off]);
      bf16x8 bloV = *reinterpret_cast<const bf16x8*>(&ldsW[off + 512]);
      acc0[ct] = __builtin_amdgcn_mfma_f32_16x16x32_bf16(av0, bhiV, acc0[ct], 0, 0, 0);
      acc1[ct] = __builtin_amdgcn_mfma_f32_16x16x32_bf16(av1, bhiV, acc1[ct], 0, 0, 0);
      acc0[ct] = __builtin_amdgcn_mfma_f32_16x16x32_bf16(av0, bloV, acc0[ct], 0, 0, 0);
      acc1[ct] = __builtin_amdgcn_mfma_f32_16x16x32_bf16(av1, bloV, acc1[ct], 0, 0, 0);
    }
  }

  int ccol = lane & 15;
  #pragma unroll
  for (int g = 0; g < 2; ++g) {
    int crow0 = rowbase + g * 16 + kgrp * 4;
    #pragma unroll
    for (int i = 0; i < 4; ++i) {
      int r = crow0 + i;
      if (r < NN) {
        float dv = dis[r];
        #pragma unroll
        for (int ct = 0; ct < 8; ++ct) {
          float v = g ? acc1[ct][i] : acc0[ct][i];
          Hs[(size_t)r * FD + ct * 16 + ccol] = f2bf(dv * v);
        }
      }
    }
  }
}

// ---------------- fused aggregation (pre-scaled rows: pure row-sum) ----------------
// AGG[n] = b + dis[n] * (Hs[n] + sum_{e: dst=n} Hs[src_e])
// Wave per node; quarter q handles edges j+q, j+q+4, j+q+8, j+q+12; each lane
// loads uint4 (8 bf16 ch). No per-edge scalars at all.

template <bool OUT32>
__global__ __launch_bounds__(256) void agg_edge_kernel(const int* __restrict__ offs,
                                                       const unsigned short* __restrict__ csr,
                                                       const float* __restrict__ dis,
                                                       const unsigned short* __restrict__ Hs,
                                                       const float* __restrict__ bias,
                                                       void* __restrict__ AGG) {
  int node = blockIdx.x * 4 + (threadIdx.x >> 6);
  if (node >= NN) return;
  node = __builtin_amdgcn_readfirstlane(node);
  int lane = threadIdx.x & 63;
  int q = lane >> 4;           // quarter 0..3
  int ch = (lane & 15) * 8;    // 8 channels per lane
  int beg = offs[node], end = offs[node + 1];
  float disn = dis[node];

  float accP[8], accQ[8];
  #pragma unroll
  for (int k = 0; k < 8; ++k) { accP[k] = 0.f; accQ[k] = 0.f; }

  if (q == 0) {  // self term (scaled by disn at the end)
    uint4 hn = *reinterpret_cast<const uint4*>(&Hs[(size_t)node * FD + ch]);
    accP[0] = blo(hn.x); accP[1] = bhi(hn.x);
    accP[2] = blo(hn.y); accP[3] = bhi(hn.y);
    accP[4] = blo(hn.z); accP[5] = bhi(hn.z);
    accP[6] = blo(hn.w); accP[7] = bhi(hn.w);
  }

  int last = end - 1;
  for (int j = beg; j < end; j += 16) {
    int e0 = j + q, e1 = j + q + 4, e2 = j + q + 8, e3 = j + q + 12;
    int i0 = (e0 <= last) ? e0 : last;
    int i1 = (e1 <= last) ? e1 : last;
    int i2 = (e2 <= last) ? e2 : last;
    int i3 = (e3 <= last) ? e3 : last;
    float m0 = (e0 <= last) ? 1.f : 0.f;
    float m1 = (e1 <= last) ? 1.f : 0.f;
    float m2 = (e2 <= last) ? 1.f : 0.f;
    float m3 = (e3 <= last) ? 1.f : 0.f;
    int s0 = csr[i0], s1 = csr[i1], s2 = csr[i2], s3 = csr[i3];
    uint4 h0 = *reinterpret_cast<const uint4*>(&Hs[(size_t)s0 * FD + ch]);
    uint4 h1 = *reinterpret_cast<const uint4*>(&Hs[(size_t)s1 * FD + ch]);
    uint4 h2 = *reinterpret_cast<const uint4*>(&Hs[(size_t)s2 * FD + ch]);
    uint4 h3 = *reinterpret_cast<const uint4*>(&Hs[(size_t)s3 * FD + ch]);
    accP[0] += m0 * blo(h0.x); accP[1] += m0 * bhi(h0.x);
    accP[2] += m0 * blo(h0.y); accP[3] += m0 * bhi(h0.y);
    accP[4] += m0 * blo(h0.z); accP[5] += m0 * bhi(h0.z);
    accP[6] += m0 * blo(h0.w); accP[7] += m0 * bhi(h0.w);
    accQ[0] += m1 * blo(h1.x); accQ[1] += m1 * bhi(h1.x);
    accQ[2] += m1 * blo(h1.y); accQ[3] += m1 * bhi(h1.y);
    accQ[4] += m1 * blo(h1.z); accQ[5] += m1 * bhi(h1.z);
    accQ[6] += m1 * blo(h1.w); accQ[7] += m1 * bhi(h1.w);
    accP[0] += m2 * blo(h2.x); accP[1] += m2 * bhi(h2.x);
    accP[2] += m2 * blo(h2.y); accP[3] += m2 * bhi(h2.y);
    accP[4] += m2 * blo(h2.z); accP[5] += m2 * bhi(h2.z);
    accP[6] += m2 * blo(h2.w); accP[7] += m2 * bhi(h2.w);
    accQ[0] += m3 * blo(h3.x); accQ[1] += m3 * bhi(h3.x);
    accQ[2] += m3 * blo(h3.y); accQ[3] += m3 * bhi(h3.y);
    accQ[4] += m3 * blo(h3.z); accQ[5] += m3 * bhi(h3.z);
    accQ[6] += m3 * blo(h3.w); accQ[7] += m3 * bhi(h3.w);
  }

  float outv[8];
  #pragma unroll
  for (int k = 0; k < 8; ++k) {
    float v = accP[k] + accQ[k];
    v += __shfl_xor(v, 16, 64);
    v += __shfl_xor(v, 32, 64);
    outv[k] = v;
  }

  if (q == 0) {
    float4 b0 = *reinterpret_cast<const float4*>(&bias[ch]);
    float4 b1 = *reinterpret_cast<const float4*>(&bias[ch + 4]);
    float o[8];
    o[0] = b0.x + disn * outv[0]; o[1] = b0.y + disn * outv[1];
    o[2] = b0.z + disn * outv[2]; o[3] = b0.w + disn * outv[3];
    o[4] = b1.x + disn * outv[4]; o[5] = b1.y + disn * outv[5];
    o[6] = b1.z + disn * outv[6]; o[7] = b1.w + disn * outv[7];
    if (OUT32) {
      float* dst = reinterpret_cast<float*>(AGG) + (size_t)node * FD + ch;
      *reinterpret_cast<float4*>(dst) = make_float4(o[0], o[1], o[2], o[3]);
      *reinterpret_cast<float4*>(dst + 4) = make_float4(o[4], o[5], o[6], o[7]);
    } else {
      uint4 pk;
      pk.x = (unsigned int)f2bf(o[0]) | ((unsigned int)f2bf(o[1]) << 16);
      pk.y = (unsigned int)f2bf(o[2]) | ((unsigned int)f2bf(o[3]) << 16);
      pk.z = (unsigned int)f2bf(o[4]) | ((unsigned int)f2bf(o[5]) << 16);
      pk.w = (unsigned int)f2bf(o[6]) | ((unsigned int)f2bf(o[7]) << 16);
      unsigned short* dst = reinterpret_cast<unsigned short*>(AGG) + (size_t)node * FD + ch;
      *reinterpret_cast<uint4*>(dst) = pk;
    }
  }
}

// ---------------- fused pooling + classifier ----------------

__device__ __forceinline__ int lower_bound(const int* __restrict__ b, int n, int key) {
  int lo = 0, hi = n;
  while (lo < hi) {
    int m = (lo + hi) >> 1;
    if (b[m] < key) lo = m + 1; else hi = m;
  }
  return lo;
}

__global__ __launch_bounds__(256) void pool_final_kernel(const float* __restrict__ AGG,
                                                         const int* __restrict__ batch,
                                                         const float* __restrict__ Wl,
                                                         const float* __restrict__ bl,
                                                         float* __restrict__ out) {
  int g = blockIdx.x;
  int tid = threadIdx.x;
  int lane = tid & 63, w = tid >> 6;
  int start = lower_bound(batch, NN, g);
  int end = lower_bound(batch, NN, g + 1);

  const float2* AGG2 = reinterpret_cast<const float2*>(AGG);
  float2 acc = make_float2(0.f, 0.f);
  for (int n = start + w; n < end; n += 4) {
    float2 v = AGG2[(size_t)n * 64 + lane];
    acc.x += v.x; acc.y += v.y;
  }
  __shared__ float red[4][FD];
  red[w][lane * 2 + 0] = acc.x;
  red[w][lane * 2 + 1] = acc.y;
  __syncthreads();
  if (w == 0) {
    float px = red[0][lane * 2] + red[1][lane * 2] + red[2][lane * 2] + red[3][lane * 2];
    float py = red[0][lane * 2 + 1] + red[1][lane * 2 + 1] + red[2][lane * 2 + 1] + red[3][lane * 2 + 1];
    float inv = 1.0f / fmaxf((float)(end - start), 1.0f);
    px *= inv; py *= inv;
    float pc[NC];
    #pragma unroll
    for (int c = 0; c < NC; ++c)
      pc[c] = px * Wl[(2 * lane) * NC + c] + py * Wl[(2 * lane + 1) * NC + c];
    #pragma unroll
    for (int off = 32; off > 0; off >>= 1) {
      #pragma unroll
      for (int c = 0; c < NC; ++c) pc[c] += __shfl_down(pc[c], off, 64);
    }
    if (lane == 0) {
      #pragma unroll
      for (int c = 0; c < NC; ++c) out[g * NC + c] = pc[c] + bl[c];
    }
  }
}

// ---------------- launch ----------------

extern "C" void kernel_launch(void* const* d_in, const int* in_sizes, int n_in,
                              void* d_out, int out_size, void* d_ws, size_t ws_size,
                              hipStream_t stream) {
  const float* x       = (const float*)d_in[0];
  const int* ei        = (const int*)d_in[1];    // int32 on device
  const int* batch     = (const int*)d_in[2];    // int32 on device
  const float* W1 = (const float*)d_in[3];
  const float* b1 = (const float*)d_in[4];
  const float* W2 = (const float*)d_in[5];
  const float* b2 = (const float*)d_in[6];
  const float* W3 = (const float*)d_in[7];
  const float* b3 = (const float*)d_in[8];
  const float* Wl = (const float*)d_in[9];
  const float* bl = (const float*)d_in[10];
  float* out = (float*)d_out;

  char* ws = (char*)d_ws;
  size_t o = 0;
  auto alloc = [&](size_t bytes) {
    void* p = ws + o;
    o += bytes;
    o = (o + 255) & ~(size_t)255;
    return p;
  };
  int*   offs   = (int*)  alloc((size_t)(NN + 1) * 4);
  float* dis    = (float*)alloc((size_t)NN * 4);
  int*   gcur   = (int*)  alloc((size_t)NBUCK * 4);
  int*   bbase  = (int*)  alloc((size_t)NBUCK * 4);
  unsigned int* bucketBuf = (unsigned int*)alloc((size_t)NBUCK * BSTRIDE * 4);
  unsigned short* csr  = (unsigned short*)alloc((size_t)NE * 2);
  unsigned short* hs   = (unsigned short*)alloc((size_t)NN * FD * 2);
  unsigned short* aggb = (unsigned short*)alloc((size_t)NN * FD * 2);
  float* aggf   = (float*)alloc((size_t)NN * FD * 4);
  unsigned short* wf1 = (unsigned short*)alloc((size_t)2 * FD * FD * 2);
  unsigned short* wf2 = (unsigned short*)alloc((size_t)2 * FD * FD * 2);
  unsigned short* wf3 = (unsigned short*)alloc((size_t)2 * FD * FD * 2);

  init_kernel<<<1, 128, 0, stream>>>(gcur);
  pass1_kernel<<<P1_BLOCKS, 1024, 0, stream>>>(ei, gcur, bucketBuf);
  bucket_scan_kernel<<<1, 128, 0, stream>>>(gcur, bbase);
  pass2_kernel<<<NBUCK, 1024, 0, stream>>>(bucketBuf, gcur, bbase, offs, dis, csr);
  prep_w_kernel<<<64, 256, 0, stream>>>(W1, wf1);
  prep_w_kernel<<<64, 256, 0, stream>>>(W2, wf2);
  prep_w_kernel<<<64, 256, 0, stream>>>(W3, wf3);

  int gemmGrid = (NN + 127) / 128;
  int nodeGrid = (NN + 3) / 4;

  // layer 1
  gemm_f32_kernel<<<gemmGrid, 256, 0, stream>>>(x, wf1, dis, hs);
  agg_edge_kernel<false><<<nodeGrid, 256, 0, stream>>>(offs, csr, dis, hs, b1, aggb);
  // layer 2
  gemm_bf16_kernel<<<gemmGrid, 256, 0, stream>>>(aggb, wf2, dis, hs);
  agg_edge_kernel<false><<<nodeGrid, 256, 0, stream>>>(offs, csr, dis, hs, b2, aggb);
  // layer 3
  gemm_bf16_kernel<<<gemmGrid, 256, 0, stream>>>(aggb, wf3, dis, hs);
  agg_edge_kernel<true><<<nodeGrid, 256, 0, stream>>>(offs, csr, dis, hs, b3, aggf);

  pool_final_kernel<<<NG, 256, 0, stream>>>(aggf, batch, Wl, bl, out);
}

// Round 10
// 172.178 us; speedup vs baseline: 1.3251x; 1.0489x over previous
//
#include <hip/hip_runtime.h>

#define NN 50000
#define NE 800000
#define FD 128
#define NG 512
#define NC 10

// bucketed CSR build
#define NBUCK 196           // ceil(50000/256)
#define BSHIFT 8            // 256 nodes per bucket
#define BSTRIDE 5120        // slots per bucket region (mean 4096, sd ~64)
#define P1_EPB 4096         // edges per pass1 block
#define P1_BLOCKS ((NE + P1_EPB - 1) / P1_EPB)  // 196

typedef __attribute__((ext_vector_type(8))) short bf16x8;
typedef __attribute__((ext_vector_type(4))) float f32x4;

// ---------------- bf16 helpers ----------------

__device__ __forceinline__ unsigned short f2bf(float f) {
  unsigned int b = __float_as_uint(f);
  b += 0x7FFF + ((b >> 16) & 1);   // round-to-nearest-even
  return (unsigned short)(b >> 16);
}
__device__ __forceinline__ float blo(unsigned int u) {
  return __uint_as_float(u << 16);
}
__device__ __forceinline__ float bhi(unsigned int u) {
  return __uint_as_float(u & 0xFFFF0000u);
}

// ---------------- setup: W fragment prep (x3) + gcursor init, one launch ----------
// wf layout: [ct(8)][ks(4)][plane(2: hi,lo)][lane(64)][j(8)] bf16
// element (k, c): k = ks*32 + (lane>>4)*8 + j ; c = ct*16 + (lane&15)

__global__ __launch_bounds__(256) void setup_kernel(const float* __restrict__ W1,
                                                    const float* __restrict__ W2,
                                                    const float* __restrict__ W3,
                                                    unsigned short* __restrict__ wf1,
                                                    unsigned short* __restrict__ wf2,
                                                    unsigned short* __restrict__ wf3,
                                                    int* __restrict__ gcursor) {
  int idx = blockIdx.x * 256 + threadIdx.x;
  if (idx < 3 * 16384) {
    int wi = idx >> 14;
    int i = idx & 16383;
    const float* W = (wi == 0) ? W1 : (wi == 1) ? W2 : W3;
    unsigned short* wf = (wi == 0) ? wf1 : (wi == 1) ? wf2 : wf3;
    int j = i & 7, l = (i >> 3) & 63, ks = (i >> 9) & 3, ct = i >> 11;
    int k = ks * 32 + (l >> 4) * 8 + j;
    int c = ct * 16 + (l & 15);
    float w = W[k * 128 + c];
    unsigned int bb = __float_as_uint(w);
    unsigned int bh = bb & 0xFFFF0000u;
    float r = w - __uint_as_float(bh);    // exact
    int base = (((ct * 4 + ks) * 2 + 0) * 64 + l) * 8 + j;
    wf[base] = (unsigned short)(bh >> 16);
    wf[base + 512] = f2bf(r);             // lo plane
  } else {
    int t = idx - 3 * 16384;
    if (t < NBUCK) gcursor[t] = t * BSTRIDE;
  }
}
#define SETUP_BLOCKS ((3 * 16384 + NBUCK + 255) / 256)

// pass1: histogram -> per-block bucket reservation -> direct scatter.
__global__ __launch_bounds__(1024) void pass1_kernel(const int* __restrict__ ei,
                                                     int* __restrict__ gcursor,
                                                     unsigned int* __restrict__ bucketBuf) {
  __shared__ int bh[NBUCK];
  __shared__ int gbase[NBUCK];
  __shared__ int bcur[NBUCK];

  int tid = threadIdx.x;
  int e0 = blockIdx.x * P1_EPB;
  int ne = NE - e0; if (ne > P1_EPB) ne = P1_EPB;

  if (tid < NBUCK) bh[tid] = 0;
  __syncthreads();

  for (int i = tid; i < ne; i += 1024) {
    int d = ei[NE + e0 + i];
    atomicAdd(&bh[d >> BSHIFT], 1);
  }
  __syncthreads();

  if (tid < NBUCK) {
    bcur[tid] = 0;
    gbase[tid] = (bh[tid] > 0) ? atomicAdd(&gcursor[tid], bh[tid]) : 0;
  }
  __syncthreads();

  for (int i = tid; i < ne; i += 1024) {
    int s = ei[e0 + i];
    int d = ei[NE + e0 + i];
    int b = d >> BSHIFT;
    int p = atomicAdd(&bcur[b], 1);
    bucketBuf[gbase[b] + p] = (unsigned int)s | ((unsigned int)d << 16);
  }
}

// pass2: inline bucket-prefix scan; per-bucket dst-sort in LDS; derives
// degree -> dis, offs; emits u16 CSR.
__global__ __launch_bounds__(1024) void pass2_kernel(const unsigned int* __restrict__ bucketBuf,
                                                     const int* __restrict__ gcur,
                                                     int* __restrict__ offs,
                                                     float* __restrict__ dis,
                                                     unsigned short* __restrict__ csr) {
  __shared__ unsigned int raw[BSTRIDE];      // 20 KB
  __shared__ unsigned short sorted[BSTRIDE]; // 10 KB
  __shared__ int h[256], pos[256], cur[256];
  __shared__ int sarr[256];

  int b = blockIdx.x;
  int tid = threadIdx.x;
  int nStart = b << BSHIFT;

  // inline inclusive scan over the 196 bucket counts
  if (tid < 256) sarr[tid] = (tid < NBUCK) ? (gcur[tid] - tid * BSTRIDE) : 0;
  __syncthreads();
  #pragma unroll
  for (int off = 1; off < 256; off <<= 1) {
    int v = 0;
    if (tid < 256 && tid >= off) v = sarr[tid - off];
    __syncthreads();
    if (tid < 256) sarr[tid] += v;
    __syncthreads();
  }
  int cntb = gcur[b] - b * BSTRIDE;
  int cnt = (cntb > BSTRIDE) ? BSTRIDE : cntb;
  int eStart = sarr[b] - cntb;     // exclusive prefix
  if (b == NBUCK - 1 && tid == 0) offs[NN] = sarr[NBUCK - 1];  // == NE

  for (int i = tid; i < cnt; i += 1024) raw[i] = bucketBuf[(size_t)b * BSTRIDE + i];
  if (tid < 256) h[tid] = 0;
  __syncthreads();

  for (int i = tid; i < cnt; i += 1024) atomicAdd(&h[(raw[i] >> 16) - nStart], 1);
  __syncthreads();

  if (tid < 256) pos[tid] = h[tid];
  __syncthreads();
  #pragma unroll
  for (int off = 1; off < 256; off <<= 1) {
    int v = 0;
    if (tid < 256 && tid >= off) v = pos[tid - off];
    __syncthreads();
    if (tid < 256) pos[tid] += v;
    __syncthreads();
  }
  if (tid < 256) {
    int ex = pos[tid] - h[tid];
    cur[tid] = ex;
    int n = nStart + tid;
    if (n < NN) {
      offs[n] = eStart + ex;
      dis[n] = rsqrtf((float)h[tid] + 1.0f);
    }
  }
  __syncthreads();

  for (int i = tid; i < cnt; i += 1024) {
    unsigned int r = raw[i];
    int d = (int)(r >> 16) - nStart;
    int p = atomicAdd(&cur[d], 1);
    sorted[p] = (unsigned short)(r & 0xFFFFu);
  }
  __syncthreads();

  for (int i = tid; i < cnt; i += 1024) csr[eStart + i] = sorted[i];
}

// ---------------- GEMM layer1: Hs(bf16) = dis * (x @ W), x fp32, 3-term ----------

__global__ __launch_bounds__(256) void gemm_f32_kernel(const float* __restrict__ A,
                                                       const unsigned short* __restrict__ wf,
                                                       const float* __restrict__ dis,
                                                       unsigned short* __restrict__ Hs) {
  __shared__ unsigned short ldsW[32768];  // 64 KB
  int tid = threadIdx.x;
  {
    const uint4* src = reinterpret_cast<const uint4*>(wf);
    uint4* dst = reinterpret_cast<uint4*>(ldsW);
    #pragma unroll
    for (int i = 0; i < 16; ++i) dst[tid + i * 256] = src[tid + i * 256];
  }
  __syncthreads();

  int w = tid >> 6, lane = tid & 63;
  int rowbase = blockIdx.x * 128 + w * 32;
  int kgrp = lane >> 4;
  int r0 = rowbase + (lane & 15);
  int r1 = r0 + 16;
  int a0 = (r0 < NN) ? r0 : 0;
  int a1 = (r1 < NN) ? r1 : 0;

  f32x4 acc0[8], acc1[8];
  #pragma unroll
  for (int ct = 0; ct < 8; ++ct) {
    f32x4 z = {0.f, 0.f, 0.f, 0.f};
    acc0[ct] = z; acc1[ct] = z;
  }

  #pragma unroll
  for (int ks = 0; ks < 4; ++ks) {
    bf16x8 ahi0, alo0, ahi1, alo1;
    {
      const float* ap = A + (size_t)a0 * FD + ks * 32 + kgrp * 8;
      float4 v0 = *reinterpret_cast<const float4*>(ap);
      float4 v1 = *reinterpret_cast<const float4*>(ap + 4);
      float a[8] = {v0.x, v0.y, v0.z, v0.w, v1.x, v1.y, v1.z, v1.w};
      #pragma unroll
      for (int j = 0; j < 8; ++j) {
        unsigned int bb = __float_as_uint(a[j]);
        unsigned int bh = bb & 0xFFFF0000u;
        float r = a[j] - __uint_as_float(bh);
        ahi0[j] = (short)(bh >> 16);
        alo0[j] = (short)f2bf(r);
      }
    }
    {
      const float* ap = A + (size_t)a1 * FD + ks * 32 + kgrp * 8;
      float4 v0 = *reinterpret_cast<const float4*>(ap);
      float4 v1 = *reinterpret_cast<const float4*>(ap + 4);
      float a[8] = {v0.x, v0.y, v0.z, v0.w, v1.x, v1.y, v1.z, v1.w};
      #pragma unroll
      for (int j = 0; j < 8; ++j) {
        unsigned int bb = __float_as_uint(a[j]);
        unsigned int bh = bb & 0xFFFF0000u;
        float r = a[j] - __uint_as_float(bh);
        ahi1[j] = (short)(bh >> 16);
        alo1[j] = (short)f2bf(r);
      }
    }
    #pragma unroll
    for (int ct = 0; ct < 8; ++ct) {
      int off = (((ct * 4 + ks) * 2) * 64 + lane) * 8;
      bf16x8 bhiV = *reinterpret_cast<const bf16x8*>(&ldsW[off]);
      bf16x8 bloV = *reinterpret_cast<const bf16x8*>(&ldsW[off + 512]);
      acc0[ct] = __builtin_amdgcn_mfma_f32_16x16x32_bf16(ahi0, bhiV, acc0[ct], 0, 0, 0);
      acc1[ct] = __builtin_amdgcn_mfma_f32_16x16x32_bf16(ahi1, bhiV, acc1[ct], 0, 0, 0);
      acc0[ct] = __builtin_amdgcn_mfma_f32_16x16x32_bf16(alo0, bhiV, acc0[ct], 0, 0, 0);
      acc1[ct] = __builtin_amdgcn_mfma_f32_16x16x32_bf16(alo1, bhiV, acc1[ct], 0, 0, 0);
      acc0[ct] = __builtin_amdgcn_mfma_f32_16x16x32_bf16(ahi0, bloV, acc0[ct], 0, 0, 0);
      acc1[ct] = __builtin_amdgcn_mfma_f32_16x16x32_bf16(ahi1, bloV, acc1[ct], 0, 0, 0);
    }
  }

  int ccol = lane & 15;
  #pragma unroll
  for (int g = 0; g < 2; ++g) {
    int crow0 = rowbase + g * 16 + kgrp * 4;
    #pragma unroll
    for (int i = 0; i < 4; ++i) {
      int r = crow0 + i;
      if (r < NN) {
        float dv = dis[r];
        #pragma unroll
        for (int ct = 0; ct < 8; ++ct) {
          float v = g ? acc1[ct][i] : acc0[ct][i];
          Hs[(size_t)r * FD + ct * 16 + ccol] = f2bf(dv * v);
        }
      }
    }
  }
}

// ---------------- GEMM layers 2/3: Hs(bf16) = dis * (relu(Ab) @ W), Ab bf16, 2-term --

__global__ __launch_bounds__(256) void gemm_bf16_kernel(const unsigned short* __restrict__ Ab,
                                                        const unsigned short* __restrict__ wf,
                                                        const float* __restrict__ dis,
                                                        unsigned short* __restrict__ Hs) {
  __shared__ unsigned short ldsW[32768];  // 64 KB
  int tid = threadIdx.x;
  {
    const uint4* src = reinterpret_cast<const uint4*>(wf);
    uint4* dst = reinterpret_cast<uint4*>(ldsW);
    #pragma unroll
    for (int i = 0; i < 16; ++i) dst[tid + i * 256] = src[tid + i * 256];
  }
  __syncthreads();

  int w = tid >> 6, lane = tid & 63;
  int rowbase = blockIdx.x * 128 + w * 32;
  int kgrp = lane >> 4;
  int r0 = rowbase + (lane & 15);
  int r1 = r0 + 16;
  int a0 = (r0 < NN) ? r0 : 0;
  int a1 = (r1 < NN) ? r1 : 0;

  f32x4 acc0[8], acc1[8];
  #pragma unroll
  for (int ct = 0; ct < 8; ++ct) {
    f32x4 z = {0.f, 0.f, 0.f, 0.f};
    acc0[ct] = z; acc1[ct] = z;
  }

  #pragma unroll
  for (int ks = 0; ks < 4; ++ks) {
    bf16x8 av0, av1;
    {
      uint4 u = *reinterpret_cast<const uint4*>(&Ab[(size_t)a0 * FD + ks * 32 + kgrp * 8]);
      unsigned int uu[4] = {u.x, u.y, u.z, u.w};
      #pragma unroll
      for (int p = 0; p < 4; ++p) {
        unsigned short lo16 = (unsigned short)(uu[p] & 0xFFFFu);
        unsigned short hi16 = (unsigned short)(uu[p] >> 16);
        av0[2 * p + 0] = (short)(((short)lo16 < 0) ? 0 : lo16);  // relu on bf16
        av0[2 * p + 1] = (short)(((short)hi16 < 0) ? 0 : hi16);
      }
    }
    {
      uint4 u = *reinterpret_cast<const uint4*>(&Ab[(size_t)a1 * FD + ks * 32 + kgrp * 8]);
      unsigned int uu[4] = {u.x, u.y, u.z, u.w};
      #pragma unroll
      for (int p = 0; p < 4; ++p) {
        unsigned short lo16 = (unsigned short)(uu[p] & 0xFFFFu);
        unsigned short hi16 = (unsigned short)(uu[p] >> 16);
        av1[2 * p + 0] = (short)(((short)lo16 < 0) ? 0 : lo16);
        av1[2 * p + 1] = (short)(((short)hi16 < 0) ? 0 : hi16);
      }
    }
    #pragma unroll
    for (int ct = 0; ct < 8; ++ct) {
      int off = (((ct * 4 + ks) * 2) * 64 + lane) * 8;
      bf16x8 bhiV = *reinterpret_cast<const bf16x8*>(&ldsW[off]);
      bf16x8 bloV = *reinterpret_cast<const bf16x8*>(&ldsW[off + 512]);
      acc0[ct] = __builtin_amdgcn_mfma_f32_16x16x32_bf16(av0, bhiV, acc0[ct], 0, 0, 0);
      acc1[ct] = __builtin_amdgcn_mfma_f32_16x16x32_bf16(av1, bhiV, acc1[ct], 0, 0, 0);
      acc0[ct] = __builtin_amdgcn_mfma_f32_16x16x32_bf16(av0, bloV, acc0[ct], 0, 0, 0);
      acc1[ct] = __builtin_amdgcn_mfma_f32_16x16x32_bf16(av1, bloV, acc1[ct], 0, 0, 0);
    }
  }

  int ccol = lane & 15;
  #pragma unroll
  for (int g = 0; g < 2; ++g) {
    int crow0 = rowbase + g * 16 + kgrp * 4;
    #pragma unroll
    for (int i = 0; i < 4; ++i) {
      int r = crow0 + i;
      if (r < NN) {
        float dv = dis[r];
        #pragma unroll
        for (int ct = 0; ct < 8; ++ct) {
          float v = g ? acc1[ct][i] : acc0[ct][i];
          Hs[(size_t)r * FD + ct * 16 + ccol] = f2bf(dv * v);
        }
      }
    }
  }
}

// ---------------- fused aggregation (pre-scaled rows: pure row-sum) ----------------
// AGG[n] = b + dis[n] * (Hs[n] + sum_{e: dst=n} Hs[src_e])

template <bool OUT32>
__global__ __launch_bounds__(256) void agg_edge_kernel(const int* __restrict__ offs,
                                                       const unsigned short* __restrict__ csr,
                                                       const float* __restrict__ dis,
                                                       const unsigned short* __restrict__ Hs,
                                                       const float* __restrict__ bias,
                                                       void* __restrict__ AGG) {
  int node = blockIdx.x * 4 + (threadIdx.x >> 6);
  if (node >= NN) return;
  node = __builtin_amdgcn_readfirstlane(node);
  int lane = threadIdx.x & 63;
  int q = lane >> 4;           // quarter 0..3
  int ch = (lane & 15) * 8;    // 8 channels per lane
  int beg = offs[node], end = offs[node + 1];
  float disn = dis[node];

  float accP[8], accQ[8];
  #pragma unroll
  for (int k = 0; k < 8; ++k) { accP[k] = 0.f; accQ[k] = 0.f; }

  if (q == 0) {  // self term
    uint4 hn = *reinterpret_cast<const uint4*>(&Hs[(size_t)node * FD + ch]);
    accP[0] = blo(hn.x); accP[1] = bhi(hn.x);
    accP[2] = blo(hn.y); accP[3] = bhi(hn.y);
    accP[4] = blo(hn.z); accP[5] = bhi(hn.z);
    accP[6] = blo(hn.w); accP[7] = bhi(hn.w);
  }

  int last = end - 1;
  for (int j = beg; j < end; j += 16) {
    int e0 = j + q, e1 = j + q + 4, e2 = j + q + 8, e3 = j + q + 12;
    int i0 = (e0 <= last) ? e0 : last;
    int i1 = (e1 <= last) ? e1 : last;
    int i2 = (e2 <= last) ? e2 : last;
    int i3 = (e3 <= last) ? e3 : last;
    float m0 = (e0 <= last) ? 1.f : 0.f;
    float m1 = (e1 <= last) ? 1.f : 0.f;
    float m2 = (e2 <= last) ? 1.f : 0.f;
    float m3 = (e3 <= last) ? 1.f : 0.f;
    int s0 = csr[i0], s1 = csr[i1], s2 = csr[i2], s3 = csr[i3];
    uint4 h0 = *reinterpret_cast<const uint4*>(&Hs[(size_t)s0 * FD + ch]);
    uint4 h1 = *reinterpret_cast<const uint4*>(&Hs[(size_t)s1 * FD + ch]);
    uint4 h2 = *reinterpret_cast<const uint4*>(&Hs[(size_t)s2 * FD + ch]);
    uint4 h3 = *reinterpret_cast<const uint4*>(&Hs[(size_t)s3 * FD + ch]);
    accP[0] += m0 * blo(h0.x); accP[1] += m0 * bhi(h0.x);
    accP[2] += m0 * blo(h0.y); accP[3] += m0 * bhi(h0.y);
    accP[4] += m0 * blo(h0.z); accP[5] += m0 * bhi(h0.z);
    accP[6] += m0 * blo(h0.w); accP[7] += m0 * bhi(h0.w);
    accQ[0] += m1 * blo(h1.x); accQ[1] += m1 * bhi(h1.x);
    accQ[2] += m1 * blo(h1.y); accQ[3] += m1 * bhi(h1.y);
    accQ[4] += m1 * blo(h1.z); accQ[5] += m1 * bhi(h1.z);
    accQ[6] += m1 * blo(h1.w); accQ[7] += m1 * bhi(h1.w);
    accP[0] += m2 * blo(h2.x); accP[1] += m2 * bhi(h2.x);
    accP[2] += m2 * blo(h2.y); accP[3] += m2 * bhi(h2.y);
    accP[4] += m2 * blo(h2.z); accP[5] += m2 * bhi(h2.z);
    accP[6] += m2 * blo(h2.w); accP[7] += m2 * bhi(h2.w);
    accQ[0] += m3 * blo(h3.x); accQ[1] += m3 * bhi(h3.x);
    accQ[2] += m3 * blo(h3.y); accQ[3] += m3 * bhi(h3.y);
    accQ[4] += m3 * blo(h3.z); accQ[5] += m3 * bhi(h3.z);
    accQ[6] += m3 * blo(h3.w); accQ[7] += m3 * bhi(h3.w);
  }

  float outv[8];
  #pragma unroll
  for (int k = 0; k < 8; ++k) {
    float v = accP[k] + accQ[k];
    v += __shfl_xor(v, 16, 64);
    v += __shfl_xor(v, 32, 64);
    outv[k] = v;
  }

  if (q == 0) {
    float4 b0 = *reinterpret_cast<const float4*>(&bias[ch]);
    float4 b1 = *reinterpret_cast<const float4*>(&bias[ch + 4]);
    float o[8];
    o[0] = b0.x + disn * outv[0]; o[1] = b0.y + disn * outv[1];
    o[2] = b0.z + disn * outv[2]; o[3] = b0.w + disn * outv[3];
    o[4] = b1.x + disn * outv[4]; o[5] = b1.y + disn * outv[5];
    o[6] = b1.z + disn * outv[6]; o[7] = b1.w + disn * outv[7];
    if (OUT32) {
      float* dst = reinterpret_cast<float*>(AGG) + (size_t)node * FD + ch;
      *reinterpret_cast<float4*>(dst) = make_float4(o[0], o[1], o[2], o[3]);
      *reinterpret_cast<float4*>(dst + 4) = make_float4(o[4], o[5], o[6], o[7]);
    } else {
      uint4 pk;
      pk.x = (unsigned int)f2bf(o[0]) | ((unsigned int)f2bf(o[1]) << 16);
      pk.y = (unsigned int)f2bf(o[2]) | ((unsigned int)f2bf(o[3]) << 16);
      pk.z = (unsigned int)f2bf(o[4]) | ((unsigned int)f2bf(o[5]) << 16);
      pk.w = (unsigned int)f2bf(o[6]) | ((unsigned int)f2bf(o[7]) << 16);
      unsigned short* dst = reinterpret_cast<unsigned short*>(AGG) + (size_t)node * FD + ch;
      *reinterpret_cast<uint4*>(dst) = pk;
    }
  }
}

// ---------------- fused pooling + classifier ----------------

__device__ __forceinline__ int lower_bound(const int* __restrict__ b, int n, int key) {
  int lo = 0, hi = n;
  while (lo < hi) {
    int m = (lo + hi) >> 1;
    if (b[m] < key) lo = m + 1; else hi = m;
  }
  return lo;
}

__global__ __launch_bounds__(256) void pool_final_kernel(const float* __restrict__ AGG,
                                                         const int* __restrict__ batch,
                                                         const float* __restrict__ Wl,
                                                         const float* __restrict__ bl,
                                                         float* __restrict__ out) {
  int g = blockIdx.x;
  int tid = threadIdx.x;
  int lane = tid & 63, w = tid >> 6;
  int start = lower_bound(batch, NN, g);
  int end = lower_bound(batch, NN, g + 1);

  const float2* AGG2 = reinterpret_cast<const float2*>(AGG);
  float2 acc = make_float2(0.f, 0.f);
  for (int n = start + w; n < end; n += 4) {
    float2 v = AGG2[(size_t)n * 64 + lane];
    acc.x += v.x; acc.y += v.y;
  }
  __shared__ float red[4][FD];
  red[w][lane * 2 + 0] = acc.x;
  red[w][lane * 2 + 1] = acc.y;
  __syncthreads();
  if (w == 0) {
    float px = red[0][lane * 2] + red[1][lane * 2] + red[2][lane * 2] + red[3][lane * 2];
    float py = red[0][lane * 2 + 1] + red[1][lane * 2 + 1] + red[2][lane * 2 + 1] + red[3][lane * 2 + 1];
    float inv = 1.0f / fmaxf((float)(end - start), 1.0f);
    px *= inv; py *= inv;
    float pc[NC];
    #pragma unroll
    for (int c = 0; c < NC; ++c)
      pc[c] = px * Wl[(2 * lane) * NC + c] + py * Wl[(2 * lane + 1) * NC + c];
    #pragma unroll
    for (int off = 32; off > 0; off >>= 1) {
      #pragma unroll
      for (int c = 0; c < NC; ++c) pc[c] += __shfl_down(pc[c], off, 64);
    }
    if (lane == 0) {
      #pragma unroll
      for (int c = 0; c < NC; ++c) out[g * NC + c] = pc[c] + bl[c];
    }
  }
}

// ---------------- launch ----------------

extern "C" void kernel_launch(void* const* d_in, const int* in_sizes, int n_in,
                              void* d_out, int out_size, void* d_ws, size_t ws_size,
                              hipStream_t stream) {
  const float* x       = (const float*)d_in[0];
  const int* ei        = (const int*)d_in[1];    // int32 on device
  const int* batch     = (const int*)d_in[2];    // int32 on device
  const float* W1 = (const float*)d_in[3];
  const float* b1 = (const float*)d_in[4];
  const float* W2 = (const float*)d_in[5];
  const float* b2 = (const float*)d_in[6];
  const float* W3 = (const float*)d_in[7];
  const float* b3 = (const float*)d_in[8];
  const float* Wl = (const float*)d_in[9];
  const float* bl = (const float*)d_in[10];
  float* out = (float*)d_out;

  char* ws = (char*)d_ws;
  size_t o = 0;
  auto alloc = [&](size_t bytes) {
    void* p = ws + o;
    o += bytes;
    o = (o + 255) & ~(size_t)255;
    return p;
  };
  int*   offs   = (int*)  alloc((size_t)(NN + 1) * 4);
  float* dis    = (float*)alloc((size_t)NN * 4);
  int*   gcur   = (int*)  alloc((size_t)NBUCK * 4);
  unsigned int* bucketBuf = (unsigned int*)alloc((size_t)NBUCK * BSTRIDE * 4);
  unsigned short* csr  = (unsigned short*)alloc((size_t)NE * 2);
  unsigned short* hs   = (unsigned short*)alloc((size_t)NN * FD * 2);
  unsigned short* aggb = (unsigned short*)alloc((size_t)NN * FD * 2);
  float* aggf   = (float*)alloc((size_t)NN * FD * 4);
  unsigned short* wf1 = (unsigned short*)alloc((size_t)2 * FD * FD * 2);
  unsigned short* wf2 = (unsigned short*)alloc((size_t)2 * FD * FD * 2);
  unsigned short* wf3 = (unsigned short*)alloc((size_t)2 * FD * FD * 2);

  setup_kernel<<<SETUP_BLOCKS, 256, 0, stream>>>(W1, W2, W3, wf1, wf2, wf3, gcur);
  pass1_kernel<<<P1_BLOCKS, 1024, 0, stream>>>(ei, gcur, bucketBuf);
  pass2_kernel<<<NBUCK, 1024, 0, stream>>>(bucketBuf, gcur, offs, dis, csr);

  int gemmGrid = (NN + 127) / 128;
  int nodeGrid = (NN + 3) / 4;

  // layer 1
  gemm_f32_kernel<<<gemmGrid, 256, 0, stream>>>(x, wf1, dis, hs);
  agg_edge_kernel<false><<<nodeGrid, 256, 0, stream>>>(offs, csr, dis, hs, b1, aggb);
  // layer 2
  gemm_bf16_kernel<<<gemmGrid, 256, 0, stream>>>(aggb, wf2, dis, hs);
  agg_edge_kernel<false><<<nodeGrid, 256, 0, stream>>>(offs, csr, dis, hs, b2, aggb);
  // layer 3
  gemm_bf16_kernel<<<gemmGrid, 256, 0, stream>>>(aggb, wf3, dis, hs);
  agg_edge_kernel<true><<<nodeGrid, 256, 0, stream>>>(offs, csr, dis, hs, b3, aggf);

  pool_final_kernel<<<NG, 256, 0, stream>>>(aggf, batch, Wl, bl, out);
}

// Round 11
// 171.471 us; speedup vs baseline: 1.3305x; 1.0041x over previous
//
#include <hip/hip_runtime.h>

#define NN 50000
#define NE 800000
#define FD 128
#define NG 512
#define NC 10

// bucketed CSR build
#define NBUCK 196           // ceil(50000/256)
#define BSHIFT 8            // 256 nodes per bucket
#define BSTRIDE 5120        // slots per bucket region (mean 4096, sd ~64)
#define P1_EPB 4096         // edges per pass1 block
#define P1_BLOCKS ((NE + P1_EPB - 1) / P1_EPB)  // 196

typedef __attribute__((ext_vector_type(8))) short bf16x8;
typedef __attribute__((ext_vector_type(4))) float f32x4;

// ---------------- bf16 helpers ----------------

__device__ __forceinline__ unsigned short f2bf(float f) {
  unsigned int b = __float_as_uint(f);
  b += 0x7FFF + ((b >> 16) & 1);   // round-to-nearest-even
  return (unsigned short)(b >> 16);
}
__device__ __forceinline__ float blo(unsigned int u) {
  return __uint_as_float(u << 16);
}
__device__ __forceinline__ float bhi(unsigned int u) {
  return __uint_as_float(u & 0xFFFF0000u);
}

// ---------------- setup: W fragment prep (x3) + gcursor init, one launch ----------

__global__ __launch_bounds__(256) void setup_kernel(const float* __restrict__ W1,
                                                    const float* __restrict__ W2,
                                                    const float* __restrict__ W3,
                                                    unsigned short* __restrict__ wf1,
                                                    unsigned short* __restrict__ wf2,
                                                    unsigned short* __restrict__ wf3,
                                                    int* __restrict__ gcursor) {
  int idx = blockIdx.x * 256 + threadIdx.x;
  if (idx < 3 * 16384) {
    int wi = idx >> 14;
    int i = idx & 16383;
    const float* W = (wi == 0) ? W1 : (wi == 1) ? W2 : W3;
    unsigned short* wf = (wi == 0) ? wf1 : (wi == 1) ? wf2 : wf3;
    int j = i & 7, l = (i >> 3) & 63, ks = (i >> 9) & 3, ct = i >> 11;
    int k = ks * 32 + (l >> 4) * 8 + j;
    int c = ct * 16 + (l & 15);
    float w = W[k * 128 + c];
    unsigned int bb = __float_as_uint(w);
    unsigned int bh = bb & 0xFFFF0000u;
    float r = w - __uint_as_float(bh);    // exact
    int base = (((ct * 4 + ks) * 2 + 0) * 64 + l) * 8 + j;
    wf[base] = (unsigned short)(bh >> 16);
    wf[base + 512] = f2bf(r);             // lo plane
  } else {
    int t = idx - 3 * 16384;
    if (t < NBUCK) gcursor[t] = t * BSTRIDE;
  }
}
#define SETUP_BLOCKS ((3 * 16384 + NBUCK + 255) / 256)

// pass1: histogram -> per-block bucket reservation -> direct scatter.
__global__ __launch_bounds__(1024) void pass1_kernel(const int* __restrict__ ei,
                                                     int* __restrict__ gcursor,
                                                     unsigned int* __restrict__ bucketBuf) {
  __shared__ int bh[NBUCK];
  __shared__ int gbase[NBUCK];
  __shared__ int bcur[NBUCK];

  int tid = threadIdx.x;
  int e0 = blockIdx.x * P1_EPB;
  int ne = NE - e0; if (ne > P1_EPB) ne = P1_EPB;

  if (tid < NBUCK) bh[tid] = 0;
  __syncthreads();

  for (int i = tid; i < ne; i += 1024) {
    int d = ei[NE + e0 + i];
    atomicAdd(&bh[d >> BSHIFT], 1);
  }
  __syncthreads();

  if (tid < NBUCK) {
    bcur[tid] = 0;
    gbase[tid] = (bh[tid] > 0) ? atomicAdd(&gcursor[tid], bh[tid]) : 0;
  }
  __syncthreads();

  for (int i = tid; i < ne; i += 1024) {
    int s = ei[e0 + i];
    int d = ei[NE + e0 + i];
    int b = d >> BSHIFT;
    int p = atomicAdd(&bcur[b], 1);
    bucketBuf[gbase[b] + p] = (unsigned int)s | ((unsigned int)d << 16);
  }
}

// pass2: inline bucket-prefix scan; per-bucket dst-sort in LDS; derives
// degree -> dis, offs; emits u16 CSR.
__global__ __launch_bounds__(1024) void pass2_kernel(const unsigned int* __restrict__ bucketBuf,
                                                     const int* __restrict__ gcur,
                                                     int* __restrict__ offs,
                                                     float* __restrict__ dis,
                                                     unsigned short* __restrict__ csr) {
  __shared__ unsigned int raw[BSTRIDE];      // 20 KB
  __shared__ unsigned short sorted[BSTRIDE]; // 10 KB
  __shared__ int h[256], pos[256], cur[256];
  __shared__ int sarr[256];

  int b = blockIdx.x;
  int tid = threadIdx.x;
  int nStart = b << BSHIFT;

  // inline inclusive scan over the 196 bucket counts
  if (tid < 256) sarr[tid] = (tid < NBUCK) ? (gcur[tid] - tid * BSTRIDE) : 0;
  __syncthreads();
  #pragma unroll
  for (int off = 1; off < 256; off <<= 1) {
    int v = 0;
    if (tid < 256 && tid >= off) v = sarr[tid - off];
    __syncthreads();
    if (tid < 256) sarr[tid] += v;
    __syncthreads();
  }
  int cntb = gcur[b] - b * BSTRIDE;
  int cnt = (cntb > BSTRIDE) ? BSTRIDE : cntb;
  int eStart = sarr[b] - cntb;     // exclusive prefix
  if (b == NBUCK - 1 && tid == 0) offs[NN] = sarr[NBUCK - 1];  // == NE

  for (int i = tid; i < cnt; i += 1024) raw[i] = bucketBuf[(size_t)b * BSTRIDE + i];
  if (tid < 256) h[tid] = 0;
  __syncthreads();

  for (int i = tid; i < cnt; i += 1024) atomicAdd(&h[(raw[i] >> 16) - nStart], 1);
  __syncthreads();

  if (tid < 256) pos[tid] = h[tid];
  __syncthreads();
  #pragma unroll
  for (int off = 1; off < 256; off <<= 1) {
    int v = 0;
    if (tid < 256 && tid >= off) v = pos[tid - off];
    __syncthreads();
    if (tid < 256) pos[tid] += v;
    __syncthreads();
  }
  if (tid < 256) {
    int ex = pos[tid] - h[tid];
    cur[tid] = ex;
    int n = nStart + tid;
    if (n < NN) {
      offs[n] = eStart + ex;
      dis[n] = rsqrtf((float)h[tid] + 1.0f);
    }
  }
  __syncthreads();

  for (int i = tid; i < cnt; i += 1024) {
    unsigned int r = raw[i];
    int d = (int)(r >> 16) - nStart;
    int p = atomicAdd(&cur[d], 1);
    sorted[p] = (unsigned short)(r & 0xFFFFu);
  }
  __syncthreads();

  for (int i = tid; i < cnt; i += 1024) csr[eStart + i] = sorted[i];
}

// ---------------- GEMM layer1: Hs(bf16) = dis * (x @ W), x fp32, 3-term ----------

__global__ __launch_bounds__(256) void gemm_f32_kernel(const float* __restrict__ A,
                                                       const unsigned short* __restrict__ wf,
                                                       const float* __restrict__ dis,
                                                       unsigned short* __restrict__ Hs) {
  __shared__ unsigned short ldsW[32768];  // 64 KB
  int tid = threadIdx.x;
  {
    const uint4* src = reinterpret_cast<const uint4*>(wf);
    uint4* dst = reinterpret_cast<uint4*>(ldsW);
    #pragma unroll
    for (int i = 0; i < 16; ++i) dst[tid + i * 256] = src[tid + i * 256];
  }
  __syncthreads();

  int w = tid >> 6, lane = tid & 63;
  int rowbase = blockIdx.x * 128 + w * 32;
  int kgrp = lane >> 4;
  int r0 = rowbase + (lane & 15);
  int r1 = r0 + 16;
  int a0 = (r0 < NN) ? r0 : 0;
  int a1 = (r1 < NN) ? r1 : 0;

  f32x4 acc0[8], acc1[8];
  #pragma unroll
  for (int ct = 0; ct < 8; ++ct) {
    f32x4 z = {0.f, 0.f, 0.f, 0.f};
    acc0[ct] = z; acc1[ct] = z;
  }

  #pragma unroll
  for (int ks = 0; ks < 4; ++ks) {
    bf16x8 ahi0, alo0, ahi1, alo1;
    {
      const float* ap = A + (size_t)a0 * FD + ks * 32 + kgrp * 8;
      float4 v0 = *reinterpret_cast<const float4*>(ap);
      float4 v1 = *reinterpret_cast<const float4*>(ap + 4);
      float a[8] = {v0.x, v0.y, v0.z, v0.w, v1.x, v1.y, v1.z, v1.w};
      #pragma unroll
      for (int j = 0; j < 8; ++j) {
        unsigned int bb = __float_as_uint(a[j]);
        unsigned int bh = bb & 0xFFFF0000u;
        float r = a[j] - __uint_as_float(bh);
        ahi0[j] = (short)(bh >> 16);
        alo0[j] = (short)f2bf(r);
      }
    }
    {
      const float* ap = A + (size_t)a1 * FD + ks * 32 + kgrp * 8;
      float4 v0 = *reinterpret_cast<const float4*>(ap);
      float4 v1 = *reinterpret_cast<const float4*>(ap + 4);
      float a[8] = {v0.x, v0.y, v0.z, v0.w, v1.x, v1.y, v1.z, v1.w};
      #pragma unroll
      for (int j = 0; j < 8; ++j) {
        unsigned int bb = __float_as_uint(a[j]);
        unsigned int bh = bb & 0xFFFF0000u;
        float r = a[j] - __uint_as_float(bh);
        ahi1[j] = (short)(bh >> 16);
        alo1[j] = (short)f2bf(r);
      }
    }
    #pragma unroll
    for (int ct = 0; ct < 8; ++ct) {
      int off = (((ct * 4 + ks) * 2) * 64 + lane) * 8;
      bf16x8 bhiV = *reinterpret_cast<const bf16x8*>(&ldsW[off]);
      bf16x8 bloV = *reinterpret_cast<const bf16x8*>(&ldsW[off + 512]);
      acc0[ct] = __builtin_amdgcn_mfma_f32_16x16x32_bf16(ahi0, bhiV, acc0[ct], 0, 0, 0);
      acc1[ct] = __builtin_amdgcn_mfma_f32_16x16x32_bf16(ahi1, bhiV, acc1[ct], 0, 0, 0);
      acc0[ct] = __builtin_amdgcn_mfma_f32_16x16x32_bf16(alo0, bhiV, acc0[ct], 0, 0, 0);
      acc1[ct] = __builtin_amdgcn_mfma_f32_16x16x32_bf16(alo1, bhiV, acc1[ct], 0, 0, 0);
      acc0[ct] = __builtin_amdgcn_mfma_f32_16x16x32_bf16(ahi0, bloV, acc0[ct], 0, 0, 0);
      acc1[ct] = __builtin_amdgcn_mfma_f32_16x16x32_bf16(ahi1, bloV, acc1[ct], 0, 0, 0);
    }
  }

  int ccol = lane & 15;
  #pragma unroll
  for (int g = 0; g < 2; ++g) {
    int crow0 = rowbase + g * 16 + kgrp * 4;
    #pragma unroll
    for (int i = 0; i < 4; ++i) {
      int r = crow0 + i;
      if (r < NN) {
        float dv = dis[r];
        #pragma unroll
        for (int ct = 0; ct < 8; ++ct) {
          float v = g ? acc1[ct][i] : acc0[ct][i];
          Hs[(size_t)r * FD + ct * 16 + ccol] = f2bf(dv * v);
        }
      }
    }
  }
}

// ---------------- GEMM layers 2/3: Hs(bf16) = dis * (relu(Ab) @ W), Ab bf16, 2-term --

__global__ __launch_bounds__(256) void gemm_bf16_kernel(const unsigned short* __restrict__ Ab,
                                                        const unsigned short* __restrict__ wf,
                                                        const float* __restrict__ dis,
                                                        unsigned short* __restrict__ Hs) {
  __shared__ unsigned short ldsW[32768];  // 64 KB
  int tid = threadIdx.x;
  {
    const uint4* src = reinterpret_cast<const uint4*>(wf);
    uint4* dst = reinterpret_cast<uint4*>(ldsW);
    #pragma unroll
    for (int i = 0; i < 16; ++i) dst[tid + i * 256] = src[tid + i * 256];
  }
  __syncthreads();

  int w = tid >> 6, lane = tid & 63;
  int rowbase = blockIdx.x * 128 + w * 32;
  int kgrp = lane >> 4;
  int r0 = rowbase + (lane & 15);
  int r1 = r0 + 16;
  int a0 = (r0 < NN) ? r0 : 0;
  int a1 = (r1 < NN) ? r1 : 0;

  f32x4 acc0[8], acc1[8];
  #pragma unroll
  for (int ct = 0; ct < 8; ++ct) {
    f32x4 z = {0.f, 0.f, 0.f, 0.f};
    acc0[ct] = z; acc1[ct] = z;
  }

  #pragma unroll
  for (int ks = 0; ks < 4; ++ks) {
    bf16x8 av0, av1;
    {
      uint4 u = *reinterpret_cast<const uint4*>(&Ab[(size_t)a0 * FD + ks * 32 + kgrp * 8]);
      unsigned int uu[4] = {u.x, u.y, u.z, u.w};
      #pragma unroll
      for (int p = 0; p < 4; ++p) {
        unsigned short lo16 = (unsigned short)(uu[p] & 0xFFFFu);
        unsigned short hi16 = (unsigned short)(uu[p] >> 16);
        av0[2 * p + 0] = (short)(((short)lo16 < 0) ? 0 : lo16);  // relu on bf16
        av0[2 * p + 1] = (short)(((short)hi16 < 0) ? 0 : hi16);
      }
    }
    {
      uint4 u = *reinterpret_cast<const uint4*>(&Ab[(size_t)a1 * FD + ks * 32 + kgrp * 8]);
      unsigned int uu[4] = {u.x, u.y, u.z, u.w};
      #pragma unroll
      for (int p = 0; p < 4; ++p) {
        unsigned short lo16 = (unsigned short)(uu[p] & 0xFFFFu);
        unsigned short hi16 = (unsigned short)(uu[p] >> 16);
        av1[2 * p + 0] = (short)(((short)lo16 < 0) ? 0 : lo16);
        av1[2 * p + 1] = (short)(((short)hi16 < 0) ? 0 : hi16);
      }
    }
    #pragma unroll
    for (int ct = 0; ct < 8; ++ct) {
      int off = (((ct * 4 + ks) * 2) * 64 + lane) * 8;
      bf16x8 bhiV = *reinterpret_cast<const bf16x8*>(&ldsW[off]);
      bf16x8 bloV = *reinterpret_cast<const bf16x8*>(&ldsW[off + 512]);
      acc0[ct] = __builtin_amdgcn_mfma_f32_16x16x32_bf16(av0, bhiV, acc0[ct], 0, 0, 0);
      acc1[ct] = __builtin_amdgcn_mfma_f32_16x16x32_bf16(av1, bhiV, acc1[ct], 0, 0, 0);
      acc0[ct] = __builtin_amdgcn_mfma_f32_16x16x32_bf16(av0, bloV, acc0[ct], 0, 0, 0);
      acc1[ct] = __builtin_amdgcn_mfma_f32_16x16x32_bf16(av1, bloV, acc1[ct], 0, 0, 0);
    }
  }

  int ccol = lane & 15;
  #pragma unroll
  for (int g = 0; g < 2; ++g) {
    int crow0 = rowbase + g * 16 + kgrp * 4;
    #pragma unroll
    for (int i = 0; i < 4; ++i) {
      int r = crow0 + i;
      if (r < NN) {
        float dv = dis[r];
        #pragma unroll
        for (int ct = 0; ct < 8; ++ct) {
          float v = g ? acc1[ct][i] : acc0[ct][i];
          Hs[(size_t)r * FD + ct * 16 + ccol] = f2bf(dv * v);
        }
      }
    }
  }
}

// ---------------- fused aggregation: 2 nodes per wave, 8 gathers in flight ----------
// AGG[n] = bf16( b + dis[n] * (Hs[n] + sum_{e: dst=n} Hs[src_e]) )

#define EDGE8(acc, h)                                        \
  acc[0] += blo(h.x); acc[1] += bhi(h.x);                    \
  acc[2] += blo(h.y); acc[3] += bhi(h.y);                    \
  acc[4] += blo(h.z); acc[5] += bhi(h.z);                    \
  acc[6] += blo(h.w); acc[7] += bhi(h.w);

#define EDGE8M(acc, h, m)                                    \
  acc[0] += m * blo(h.x); acc[1] += m * bhi(h.x);            \
  acc[2] += m * blo(h.y); acc[3] += m * bhi(h.y);            \
  acc[4] += m * blo(h.z); acc[5] += m * bhi(h.z);            \
  acc[6] += m * blo(h.w); acc[7] += m * bhi(h.w);

__global__ __launch_bounds__(256) void agg_edge_kernel(const int* __restrict__ offs,
                                                       const unsigned short* __restrict__ csr,
                                                       const float* __restrict__ dis,
                                                       const unsigned short* __restrict__ Hs,
                                                       const float* __restrict__ bias,
                                                       unsigned short* __restrict__ AGG) {
  int pair = blockIdx.x * 4 + (threadIdx.x >> 6);   // wave id; 2 nodes per wave
  int n0 = pair * 2;
  if (n0 >= NN) return;
  n0 = __builtin_amdgcn_readfirstlane(n0);
  int n1 = n0 + 1;                                  // NN even -> always valid
  int lane = threadIdx.x & 63;
  int q = lane >> 4;           // quarter 0..3
  int ch = (lane & 15) * 8;    // 8 channels per lane

  int beg0 = offs[n0], end0 = offs[n0 + 1];
  int beg1 = end0,     end1 = offs[n1 + 1];         // offs[n1] == offs[n0+1]

  float a0[8], a1[8];
  #pragma unroll
  for (int k = 0; k < 8; ++k) { a0[k] = 0.f; a1[k] = 0.f; }

  // self terms: quarter 0 takes node0's row, quarter 1 takes node1's row
  if (q == 0) {
    uint4 hn = *reinterpret_cast<const uint4*>(&Hs[(size_t)n0 * FD + ch]);
    EDGE8(a0, hn);
  } else if (q == 1) {
    uint4 hn = *reinterpret_cast<const uint4*>(&Hs[(size_t)n1 * FD + ch]);
    EDGE8(a1, hn);
  }

  int j0 = beg0, j1 = beg1;
  // fused unmasked dual loop: 16 edges per node per iter, 8 loads in flight
  int it = min((end0 - j0) >> 4, (end1 - j1) >> 4);
  for (int t = 0; t < it; ++t) {
    int s00 = csr[j0 + q], s01 = csr[j0 + q + 4], s02 = csr[j0 + q + 8], s03 = csr[j0 + q + 12];
    int s10 = csr[j1 + q], s11 = csr[j1 + q + 4], s12 = csr[j1 + q + 8], s13 = csr[j1 + q + 12];
    uint4 h00 = *reinterpret_cast<const uint4*>(&Hs[(size_t)s00 * FD + ch]);
    uint4 h01 = *reinterpret_cast<const uint4*>(&Hs[(size_t)s01 * FD + ch]);
    uint4 h02 = *reinterpret_cast<const uint4*>(&Hs[(size_t)s02 * FD + ch]);
    uint4 h03 = *reinterpret_cast<const uint4*>(&Hs[(size_t)s03 * FD + ch]);
    uint4 h10 = *reinterpret_cast<const uint4*>(&Hs[(size_t)s10 * FD + ch]);
    uint4 h11 = *reinterpret_cast<const uint4*>(&Hs[(size_t)s11 * FD + ch]);
    uint4 h12 = *reinterpret_cast<const uint4*>(&Hs[(size_t)s12 * FD + ch]);
    uint4 h13 = *reinterpret_cast<const uint4*>(&Hs[(size_t)s13 * FD + ch]);
    EDGE8(a0, h00); EDGE8(a0, h01); EDGE8(a0, h02); EDGE8(a0, h03);
    EDGE8(a1, h10); EDGE8(a1, h11); EDGE8(a1, h12); EDGE8(a1, h13);
    j0 += 16; j1 += 16;
  }
  // node0 remainder (masked 16-edge chunks)
  for (; j0 < end0; j0 += 16) {
    int last = end0 - 1;
    int e0 = j0 + q, e1 = j0 + q + 4, e2 = j0 + q + 8, e3 = j0 + q + 12;
    int i0 = (e0 <= last) ? e0 : 0, i1 = (e1 <= last) ? e1 : 0;
    int i2 = (e2 <= last) ? e2 : 0, i3 = (e3 <= last) ? e3 : 0;
    float m0 = (e0 <= last) ? 1.f : 0.f, m1 = (e1 <= last) ? 1.f : 0.f;
    float m2 = (e2 <= last) ? 1.f : 0.f, m3 = (e3 <= last) ? 1.f : 0.f;
    int s0 = csr[i0], s1 = csr[i1], s2 = csr[i2], s3 = csr[i3];
    uint4 h0 = *reinterpret_cast<const uint4*>(&Hs[(size_t)s0 * FD + ch]);
    uint4 h1 = *reinterpret_cast<const uint4*>(&Hs[(size_t)s1 * FD + ch]);
    uint4 h2 = *reinterpret_cast<const uint4*>(&Hs[(size_t)s2 * FD + ch]);
    uint4 h3 = *reinterpret_cast<const uint4*>(&Hs[(size_t)s3 * FD + ch]);
    EDGE8M(a0, h0, m0); EDGE8M(a0, h1, m1); EDGE8M(a0, h2, m2); EDGE8M(a0, h3, m3);
  }
  // node1 remainder
  for (; j1 < end1; j1 += 16) {
    int last = end1 - 1;
    int e0 = j1 + q, e1 = j1 + q + 4, e2 = j1 + q + 8, e3 = j1 + q + 12;
    int i0 = (e0 <= last) ? e0 : 0, i1 = (e1 <= last) ? e1 : 0;
    int i2 = (e2 <= last) ? e2 : 0, i3 = (e3 <= last) ? e3 : 0;
    float m0 = (e0 <= last) ? 1.f : 0.f, m1 = (e1 <= last) ? 1.f : 0.f;
    float m2 = (e2 <= last) ? 1.f : 0.f, m3 = (e3 <= last) ? 1.f : 0.f;
    int s0 = csr[i0], s1 = csr[i1], s2 = csr[i2], s3 = csr[i3];
    uint4 h0 = *reinterpret_cast<const uint4*>(&Hs[(size_t)s0 * FD + ch]);
    uint4 h1 = *reinterpret_cast<const uint4*>(&Hs[(size_t)s1 * FD + ch]);
    uint4 h2 = *reinterpret_cast<const uint4*>(&Hs[(size_t)s2 * FD + ch]);
    uint4 h3 = *reinterpret_cast<const uint4*>(&Hs[(size_t)s3 * FD + ch]);
    EDGE8M(a1, h0, m0); EDGE8M(a1, h1, m1); EDGE8M(a1, h2, m2); EDGE8M(a1, h3, m3);
  }

  // cross-quarter reduction for both nodes
  #pragma unroll
  for (int k = 0; k < 8; ++k) {
    float v0 = a0[k];
    v0 += __shfl_xor(v0, 16, 64);
    v0 += __shfl_xor(v0, 32, 64);
    a0[k] = v0;
    float v1 = a1[k];
    v1 += __shfl_xor(v1, 16, 64);
    v1 += __shfl_xor(v1, 32, 64);
    a1[k] = v1;
  }

  if (q < 2) {
    int n = q ? n1 : n0;
    float dn = dis[n];
    const float* acc = q ? a1 : a0;
    float4 b0 = *reinterpret_cast<const float4*>(&bias[ch]);
    float4 b1 = *reinterpret_cast<const float4*>(&bias[ch + 4]);
    float o[8];
    o[0] = b0.x + dn * acc[0]; o[1] = b0.y + dn * acc[1];
    o[2] = b0.z + dn * acc[2]; o[3] = b0.w + dn * acc[3];
    o[4] = b1.x + dn * acc[4]; o[5] = b1.y + dn * acc[5];
    o[6] = b1.z + dn * acc[6]; o[7] = b1.w + dn * acc[7];
    uint4 pk;
    pk.x = (unsigned int)f2bf(o[0]) | ((unsigned int)f2bf(o[1]) << 16);
    pk.y = (unsigned int)f2bf(o[2]) | ((unsigned int)f2bf(o[3]) << 16);
    pk.z = (unsigned int)f2bf(o[4]) | ((unsigned int)f2bf(o[5]) << 16);
    pk.w = (unsigned int)f2bf(o[6]) | ((unsigned int)f2bf(o[7]) << 16);
    *reinterpret_cast<uint4*>(&AGG[(size_t)n * FD + ch]) = pk;
  }
}

// ---------------- fused pooling + classifier (bf16 AGG input) ----------------

__device__ __forceinline__ int lower_bound(const int* __restrict__ b, int n, int key) {
  int lo = 0, hi = n;
  while (lo < hi) {
    int m = (lo + hi) >> 1;
    if (b[m] < key) lo = m + 1; else hi = m;
  }
  return lo;
}

__global__ __launch_bounds__(256) void pool_final_kernel(const unsigned short* __restrict__ AGG,
                                                         const int* __restrict__ batch,
                                                         const float* __restrict__ Wl,
                                                         const float* __restrict__ bl,
                                                         float* __restrict__ out) {
  int g = blockIdx.x;
  int tid = threadIdx.x;
  int lane = tid & 63, w = tid >> 6;
  int start = lower_bound(batch, NN, g);
  int end = lower_bound(batch, NN, g + 1);

  float2 acc = make_float2(0.f, 0.f);
  for (int n = start + w; n < end; n += 4) {
    unsigned int v = *reinterpret_cast<const unsigned int*>(&AGG[(size_t)n * FD + lane * 2]);
    acc.x += blo(v);
    acc.y += bhi(v);
  }
  __shared__ float red[4][FD];
  red[w][lane * 2 + 0] = acc.x;
  red[w][lane * 2 + 1] = acc.y;
  __syncthreads();
  if (w == 0) {
    float px = red[0][lane * 2] + red[1][lane * 2] + red[2][lane * 2] + red[3][lane * 2];
    float py = red[0][lane * 2 + 1] + red[1][lane * 2 + 1] + red[2][lane * 2 + 1] + red[3][lane * 2 + 1];
    float inv = 1.0f / fmaxf((float)(end - start), 1.0f);
    px *= inv; py *= inv;
    float pc[NC];
    #pragma unroll
    for (int c = 0; c < NC; ++c)
      pc[c] = px * Wl[(2 * lane) * NC + c] + py * Wl[(2 * lane + 1) * NC + c];
    #pragma unroll
    for (int off = 32; off > 0; off >>= 1) {
      #pragma unroll
      for (int c = 0; c < NC; ++c) pc[c] += __shfl_down(pc[c], off, 64);
    }
    if (lane == 0) {
      #pragma unroll
      for (int c = 0; c < NC; ++c) out[g * NC + c] = pc[c] + bl[c];
    }
  }
}

// ---------------- launch ----------------

extern "C" void kernel_launch(void* const* d_in, const int* in_sizes, int n_in,
                              void* d_out, int out_size, void* d_ws, size_t ws_size,
                              hipStream_t stream) {
  const float* x       = (const float*)d_in[0];
  const int* ei        = (const int*)d_in[1];    // int32 on device
  const int* batch     = (const int*)d_in[2];    // int32 on device
  const float* W1 = (const float*)d_in[3];
  const float* b1 = (const float*)d_in[4];
  const float* W2 = (const float*)d_in[5];
  const float* b2 = (const float*)d_in[6];
  const float* W3 = (const float*)d_in[7];
  const float* b3 = (const float*)d_in[8];
  const float* Wl = (const float*)d_in[9];
  const float* bl = (const float*)d_in[10];
  float* out = (float*)d_out;

  char* ws = (char*)d_ws;
  size_t o = 0;
  auto alloc = [&](size_t bytes) {
    void* p = ws + o;
    o += bytes;
    o = (o + 255) & ~(size_t)255;
    return p;
  };
  int*   offs   = (int*)  alloc((size_t)(NN + 1) * 4);
  float* dis    = (float*)alloc((size_t)NN * 4);
  int*   gcur   = (int*)  alloc((size_t)NBUCK * 4);
  unsigned int* bucketBuf = (unsigned int*)alloc((size_t)NBUCK * BSTRIDE * 4);
  unsigned short* csr  = (unsigned short*)alloc((size_t)NE * 2 + 64);
  unsigned short* hs   = (unsigned short*)alloc((size_t)NN * FD * 2);
  unsigned short* aggb = (unsigned short*)alloc((size_t)NN * FD * 2);
  unsigned short* wf1 = (unsigned short*)alloc((size_t)2 * FD * FD * 2);
  unsigned short* wf2 = (unsigned short*)alloc((size_t)2 * FD * FD * 2);
  unsigned short* wf3 = (unsigned short*)alloc((size_t)2 * FD * FD * 2);

  setup_kernel<<<SETUP_BLOCKS, 256, 0, stream>>>(W1, W2, W3, wf1, wf2, wf3, gcur);
  pass1_kernel<<<P1_BLOCKS, 1024, 0, stream>>>(ei, gcur, bucketBuf);
  pass2_kernel<<<NBUCK, 1024, 0, stream>>>(bucketBuf, gcur, offs, dis, csr);

  int gemmGrid = (NN + 127) / 128;
  int aggGrid = (NN / 2 + 3) / 4;   // 2 nodes per wave, 4 waves per block

  // layer 1
  gemm_f32_kernel<<<gemmGrid, 256, 0, stream>>>(x, wf1, dis, hs);
  agg_edge_kernel<<<aggGrid, 256, 0, stream>>>(offs, csr, dis, hs, b1, aggb);
  // layer 2
  gemm_bf16_kernel<<<gemmGrid, 256, 0, stream>>>(aggb, wf2, dis, hs);
  agg_edge_kernel<<<aggGrid, 256, 0, stream>>>(offs, csr, dis, hs, b2, aggb);
  // layer 3
  gemm_bf16_kernel<<<gemmGrid, 256, 0, stream>>>(aggb, wf3, dis, hs);
  agg_edge_kernel<<<aggGrid, 256, 0, stream>>>(offs, csr, dis, hs, b3, aggb);

  pool_final_kernel<<<NG, 256, 0, stream>>>(aggb, batch, Wl, bl, out);
}